// Round 1
// baseline (520.921 us; speedup 1.0000x reference)
//
#include <hip/hip_runtime.h>
#include <hip/hip_bf16.h>

#define LRELU_SLOPE 0.2f

// ---------------------------------------------------------------------------
// CSR build: degree count -> single-block scan -> scatter
// ---------------------------------------------------------------------------
__global__ void zero_int_kernel(int* __restrict__ p, int n) {
    int i = blockIdx.x * 256 + threadIdx.x;
    if (i < n) p[i] = 0;
}

__global__ void degree_kernel(const int* __restrict__ dst, int E, int N,
                              int* __restrict__ deg) {
    int i = blockIdx.x * 256 + threadIdx.x;
    int total = E + N;
    if (i >= total) return;
    int d = (i < E) ? dst[i] : (i - E);   // self-loops appended
    atomicAdd(&deg[d], 1);
}

__global__ __launch_bounds__(1024) void scan_kernel(const int* __restrict__ deg,
                                                    int* __restrict__ ptr,
                                                    int* __restrict__ ptr_copy,
                                                    int N) {
    __shared__ int tile[1024];
    __shared__ int carry;
    if (threadIdx.x == 0) carry = 0;
    __syncthreads();
    for (int base = 0; base < N; base += 1024) {
        int i = base + (int)threadIdx.x;
        int v = (i < N) ? deg[i] : 0;
        tile[threadIdx.x] = v;
        __syncthreads();
        // Hillis-Steele inclusive scan
        for (int off = 1; off < 1024; off <<= 1) {
            int t = 0;
            if (threadIdx.x >= (unsigned)off) t = tile[threadIdx.x - off];
            __syncthreads();
            if (threadIdx.x >= (unsigned)off) tile[threadIdx.x] += t;
            __syncthreads();
        }
        int incl = tile[threadIdx.x];
        int excl = incl - v;
        int c = carry;
        __syncthreads();
        if (i < N) { ptr[i] = c + excl; ptr_copy[i] = c + excl; }
        if (threadIdx.x == 1023) carry = c + incl;
        __syncthreads();
    }
    if (threadIdx.x == 0) ptr[N] = carry;
}

__global__ void scatter_kernel(const int* __restrict__ src,
                               const int* __restrict__ dst, int E, int N,
                               int* __restrict__ ptr_copy,
                               int* __restrict__ csr_src) {
    int i = blockIdx.x * 256 + threadIdx.x;
    int total = E + N;
    if (i >= total) return;
    int s, d;
    if (i < E) { s = src[i]; d = dst[i]; }
    else       { s = d = i - E; }
    int pos = atomicAdd(&ptr_copy[d], 1);
    csr_src[pos] = s;
}

// ---------------------------------------------------------------------------
// GEMM1: [N,128] @ [128,128] -> [N,128].  16 nodes/block, 256 threads.
// ---------------------------------------------------------------------------
__global__ __launch_bounds__(256) void gemm1_kernel(const float* __restrict__ x,
                                                    const float* __restrict__ W,
                                                    float* __restrict__ out) {
    __shared__ float xs[16][128];
    int n0  = blockIdx.x * 16;
    int col = threadIdx.x & 127;
    int grp = threadIdx.x >> 7;   // 0..1
    // cooperative load of 16 rows (2048 floats = 512 float4)
    const float4* xv = (const float4*)(x + (size_t)n0 * 128);
    float4* xsv = (float4*)(&xs[0][0]);
    for (int i = threadIdx.x; i < 512; i += 256) xsv[i] = xv[i];
    __syncthreads();

    float acc[8] = {0.f,0.f,0.f,0.f,0.f,0.f,0.f,0.f};
    for (int kk = 0; kk < 128; kk += 4) {
        float w0 = W[(kk + 0) * 128 + col];
        float w1 = W[(kk + 1) * 128 + col];
        float w2 = W[(kk + 2) * 128 + col];
        float w3 = W[(kk + 3) * 128 + col];
#pragma unroll
        for (int r = 0; r < 8; r++) {
            float4 v = *(const float4*)&xs[grp + 2 * r][kk];
            acc[r] += v.x * w0 + v.y * w1 + v.z * w2 + v.w * w3;
        }
    }
#pragma unroll
    for (int r = 0; r < 8; r++)
        out[(size_t)(n0 + grp + 2 * r) * 128 + col] = acc[r];
}

// ---------------------------------------------------------------------------
// GEMM2: [N,128] @ [128,32] -> [N,32].  32 nodes/block, 256 threads.
// ---------------------------------------------------------------------------
__global__ __launch_bounds__(256) void gemm2_kernel(const float* __restrict__ x,
                                                    const float* __restrict__ W,
                                                    float* __restrict__ out, int N) {
    __shared__ float xs[32][128];
    int n0  = blockIdx.x * 32;
    int col = threadIdx.x & 31;
    int grp = threadIdx.x >> 5;   // 0..7
    const float4* xv = (const float4*)(x + (size_t)n0 * 128);
    float4* xsv = (float4*)(&xs[0][0]);
    int limit = (N - n0) * 32;    // valid float4 count in this tile
    for (int i = threadIdx.x; i < 1024; i += 256) {
        float4 v = make_float4(0.f, 0.f, 0.f, 0.f);
        if (i < limit) v = xv[i];
        xsv[i] = v;
    }
    __syncthreads();

    float acc[4] = {0.f,0.f,0.f,0.f};
    for (int kk = 0; kk < 128; kk += 4) {
        float w0 = W[(kk + 0) * 32 + col];
        float w1 = W[(kk + 1) * 32 + col];
        float w2 = W[(kk + 2) * 32 + col];
        float w3 = W[(kk + 3) * 32 + col];
#pragma unroll
        for (int r = 0; r < 4; r++) {
            float4 v = *(const float4*)&xs[grp + 8 * r][kk];
            acc[r] += v.x * w0 + v.y * w1 + v.z * w2 + v.w * w3;
        }
    }
#pragma unroll
    for (int r = 0; r < 4; r++) {
        int n = n0 + grp + 8 * r;
        if (n < N) out[(size_t)n * 32 + col] = acc[r];
    }
}

// ---------------------------------------------------------------------------
// Attention logit dots, layer 1: per (node,head): es = <h, a_src>, ed = <h, a_dst>
// h1 layout [n][h][c] flat => row t = n*4+h starts at t*32.
// ---------------------------------------------------------------------------
__global__ void dots1_kernel(const float* __restrict__ h1,
                             const float* __restrict__ a_src,
                             const float* __restrict__ a_dst,
                             float* __restrict__ es, float* __restrict__ ed,
                             int N4) {
    int t = blockIdx.x * 256 + threadIdx.x;
    if (t >= N4) return;
    int h = t & 3;
    const float4* hp = (const float4*)(h1 + (size_t)t * 32);
    const float4* ap = (const float4*)(a_src + h * 32);
    const float4* bp = (const float4*)(a_dst + h * 32);
    float s = 0.f, d = 0.f;
#pragma unroll
    for (int j = 0; j < 8; j++) {
        float4 v = hp[j], a = ap[j], b = bp[j];
        s += v.x * a.x + v.y * a.y + v.z * a.z + v.w * a.w;
        d += v.x * b.x + v.y * b.y + v.z * b.z + v.w * b.w;
    }
    es[t] = s; ed[t] = d;
}

__global__ void dots2_kernel(const float* __restrict__ h2,
                             const float* __restrict__ a_src,
                             const float* __restrict__ a_dst,
                             float* __restrict__ es, float* __restrict__ ed,
                             int N) {
    int t = blockIdx.x * 256 + threadIdx.x;
    if (t >= N) return;
    const float4* hp = (const float4*)(h2 + (size_t)t * 32);
    const float4* ap = (const float4*)a_src;
    const float4* bp = (const float4*)a_dst;
    float s = 0.f, d = 0.f;
#pragma unroll
    for (int j = 0; j < 8; j++) {
        float4 v = hp[j], a = ap[j], b = bp[j];
        s += v.x * a.x + v.y * a.y + v.z * a.z + v.w * a.w;
        d += v.x * b.x + v.y * b.y + v.z * b.z + v.w * b.w;
    }
    es[t] = s; ed[t] = d;
}

// ---------------------------------------------------------------------------
// Aggregation layer 1: per dst node (block), 128 threads = 128 channels.
// Single pass: acc_c = sum_e w_e * h1[src_e, c];  wsum_h = sum_e w_e
// out = elu(acc/wsum + b1)  -> h1e (input to layer 2)
// Softmax without max-subtraction (logits bounded, exp can't overflow).
// ---------------------------------------------------------------------------
__global__ __launch_bounds__(128) void agg1_kernel(
        const float* __restrict__ h1, const float* __restrict__ es,
        const float* __restrict__ ed, const int* __restrict__ ptr,
        const int* __restrict__ csr_src, const float* __restrict__ b1,
        float* __restrict__ h1e) {
    int n = blockIdx.x;
    int c = threadIdx.x;          // 0..127
    int h = c >> 5;               // head
    float edl  = ed[n * 4 + h];
    int start = ptr[n], end = ptr[n + 1];
    float acc = 0.f, wsum = 0.f;
    for (int i = start; i < end; i++) {
        int s = csr_src[i];
        float l = es[s * 4 + h] + edl;
        l = l > 0.f ? l : LRELU_SLOPE * l;
        float w = __expf(l);
        wsum += w;
        acc += w * h1[(size_t)s * 128 + c];
    }
    float o = acc / wsum + b1[c];
    h1e[(size_t)n * 128 + c] = o > 0.f ? o : __expf(o) - 1.f;
}

// ---------------------------------------------------------------------------
// Aggregation layer 2: 4 nodes/block of 128 threads, 32 channels each, 1 head.
// out = acc/wsum + b2   (mean over 1 head == identity, no activation)
// ---------------------------------------------------------------------------
__global__ __launch_bounds__(128) void agg2_kernel(
        const float* __restrict__ h2, const float* __restrict__ es,
        const float* __restrict__ ed, const int* __restrict__ ptr,
        const int* __restrict__ csr_src, const float* __restrict__ b2,
        float* __restrict__ out, int N) {
    int n = blockIdx.x * 4 + (threadIdx.x >> 5);
    if (n >= N) return;
    int c = threadIdx.x & 31;
    float edl = ed[n];
    int start = ptr[n], end = ptr[n + 1];
    float acc = 0.f, wsum = 0.f;
    for (int i = start; i < end; i++) {
        int s = csr_src[i];
        float l = es[s] + edl;
        l = l > 0.f ? l : LRELU_SLOPE * l;
        float w = __expf(l);
        wsum += w;
        acc += w * h2[(size_t)s * 32 + c];
    }
    out[(size_t)n * 32 + c] = acc / wsum + b2[c];
}

// ---------------------------------------------------------------------------
extern "C" void kernel_launch(void* const* d_in, const int* in_sizes, int n_in,
                              void* d_out, int out_size, void* d_ws, size_t ws_size,
                              hipStream_t stream) {
    const float* x      = (const float*)d_in[0];
    const int*   ei     = (const int*)  d_in[1];
    const float* W1     = (const float*)d_in[2];
    const float* a_src1 = (const float*)d_in[3];
    const float* a_dst1 = (const float*)d_in[4];
    const float* b1     = (const float*)d_in[5];
    const float* W2     = (const float*)d_in[6];
    const float* a_src2 = (const float*)d_in[7];
    const float* a_dst2 = (const float*)d_in[8];
    const float* b2     = (const float*)d_in[9];
    float* outp = (float*)d_out;

    const int N = in_sizes[0] / 128;   // 50000
    const int E = in_sizes[1] / 2;     // 800000
    const int Etot = E + N;            // with self-loops

    const int* src = ei;
    const int* dst = ei + E;

    // workspace layout (bytes)
    char* w = (char*)d_ws;
    float* h1raw   = (float*)(w + 0);                       // N*128*4 = 25,600,000
    float* h1e     = (float*)(w + 25600000);                // N*128*4
    float* h2      = (float*)(w + 51200000);                // N*32*4  =  6,400,000
    float* es1     = (float*)(w + 57600000);                // N*4*4   =    800,000
    float* ed1     = (float*)(w + 58400000);                // N*4*4
    float* es2     = (float*)(w + 59200000);                // N*4     =    200,000
    float* ed2     = (float*)(w + 59400000);                // N*4
    int*   deg     = (int*)  (w + 59600000);                // N*4 (+pad)
    int*   ptr     = (int*)  (w + 59800064);                // (N+1)*4 (+pad)
    int*   ptrcp   = (int*)  (w + 60000128);                // N*4 (+pad)
    int*   csr_src = (int*)  (w + 60200192);                // Etot*4 = 3,400,000

    // --- CSR build (shared by both layers) ---
    zero_int_kernel<<<(N + 255) / 256, 256, 0, stream>>>(deg, N);
    degree_kernel<<<(Etot + 255) / 256, 256, 0, stream>>>(dst, E, N, deg);
    scan_kernel<<<1, 1024, 0, stream>>>(deg, ptr, ptrcp, N);
    scatter_kernel<<<(Etot + 255) / 256, 256, 0, stream>>>(src, dst, E, N, ptrcp, csr_src);

    // --- Layer 1 ---
    gemm1_kernel<<<N / 16, 256, 0, stream>>>(x, W1, h1raw);
    dots1_kernel<<<(N * 4 + 255) / 256, 256, 0, stream>>>(h1raw, a_src1, a_dst1, es1, ed1, N * 4);
    agg1_kernel<<<N, 128, 0, stream>>>(h1raw, es1, ed1, ptr, csr_src, b1, h1e);

    // --- Layer 2 ---
    gemm2_kernel<<<(N + 31) / 32, 256, 0, stream>>>(h1e, W2, h2, N);
    dots2_kernel<<<(N + 255) / 256, 256, 0, stream>>>(h2, a_src2, a_dst2, es2, ed2, N);
    agg2_kernel<<<(N + 3) / 4, 128, 0, stream>>>(h2, es2, ed2, ptr, csr_src, b2, outp, N);
}

// Round 2
// 375.048 us; speedup vs baseline: 1.3889x; 1.3889x over previous
//
#include <hip/hip_runtime.h>
#include <hip/hip_bf16.h>

#define LRELU_SLOPE 0.2f

// ---------------------------------------------------------------------------
// CSR build: degree count -> two-level parallel scan -> scatter
// ---------------------------------------------------------------------------
__global__ void zero_int_kernel(int* __restrict__ p, int n) {
    int i = blockIdx.x * 256 + threadIdx.x;
    if (i < n) p[i] = 0;
}

__global__ void degree_kernel(const int* __restrict__ dst, int E, int N,
                              int* __restrict__ deg) {
    int i = blockIdx.x * 256 + threadIdx.x;
    int total = E + N;
    if (i >= total) return;
    int d = (i < E) ? dst[i] : (i - E);   // self-loops appended
    atomicAdd(&deg[d], 1);
}

// Level A: per-block (1024) exclusive scan, partials into ptr, totals to bsum
__global__ __launch_bounds__(1024) void scanA_kernel(const int* __restrict__ deg,
                                                     int* __restrict__ ptr,
                                                     int* __restrict__ bsum, int N) {
    __shared__ int tile[1024];
    int i = blockIdx.x * 1024 + threadIdx.x;
    int v = (i < N) ? deg[i] : 0;
    tile[threadIdx.x] = v;
    __syncthreads();
    for (int off = 1; off < 1024; off <<= 1) {
        int t = (threadIdx.x >= (unsigned)off) ? tile[threadIdx.x - off] : 0;
        __syncthreads();
        tile[threadIdx.x] += t;
        __syncthreads();
    }
    int incl = tile[threadIdx.x];
    if (i < N) ptr[i] = incl - v;                    // block-local exclusive
    if (threadIdx.x == 1023) bsum[blockIdx.x] = incl;
}

// Level B: single small block scans the <=256 block sums in-place (exclusive)
__global__ __launch_bounds__(256) void scanB_kernel(int* __restrict__ bsum, int nb) {
    __shared__ int tile[256];
    int v = (threadIdx.x < (unsigned)nb) ? bsum[threadIdx.x] : 0;
    tile[threadIdx.x] = v;
    __syncthreads();
    for (int off = 1; off < 256; off <<= 1) {
        int t = (threadIdx.x >= (unsigned)off) ? tile[threadIdx.x - off] : 0;
        __syncthreads();
        tile[threadIdx.x] += t;
        __syncthreads();
    }
    if (threadIdx.x < (unsigned)nb) bsum[threadIdx.x] = tile[threadIdx.x] - v;
}

// Level C: apply block offsets; also produce scatter cursor (reuses deg buffer)
__global__ void scanC_kernel(int* __restrict__ ptr, int* __restrict__ cursor,
                             const int* __restrict__ boff, int N, int Etot) {
    int i = blockIdx.x * 256 + threadIdx.x;
    if (i == 0) ptr[N] = Etot;
    if (i >= N) return;
    int p = ptr[i] + boff[i >> 10];
    ptr[i] = p;
    cursor[i] = p;
}

__global__ void scatter_kernel(const int* __restrict__ src,
                               const int* __restrict__ dst, int E, int N,
                               int* __restrict__ cursor,
                               int* __restrict__ csr_src) {
    int i = blockIdx.x * 256 + threadIdx.x;
    int total = E + N;
    if (i >= total) return;
    int s, d;
    if (i < E) { s = src[i]; d = dst[i]; }
    else       { s = d = i - E; }
    int pos = atomicAdd(&cursor[d], 1);
    csr_src[pos] = s;
}

// ---------------------------------------------------------------------------
// GEMM1: [N,128] @ [128,128] -> [N,128].  16 nodes/block, 256 threads.
// ---------------------------------------------------------------------------
__global__ __launch_bounds__(256) void gemm1_kernel(const float* __restrict__ x,
                                                    const float* __restrict__ W,
                                                    float* __restrict__ out) {
    __shared__ float xs[16][128];
    int n0  = blockIdx.x * 16;
    int col = threadIdx.x & 127;
    int grp = threadIdx.x >> 7;   // 0..1
    const float4* xv = (const float4*)(x + (size_t)n0 * 128);
    float4* xsv = (float4*)(&xs[0][0]);
    for (int i = threadIdx.x; i < 512; i += 256) xsv[i] = xv[i];
    __syncthreads();

    float acc[8] = {0.f,0.f,0.f,0.f,0.f,0.f,0.f,0.f};
    for (int kk = 0; kk < 128; kk += 4) {
        float w0 = W[(kk + 0) * 128 + col];
        float w1 = W[(kk + 1) * 128 + col];
        float w2 = W[(kk + 2) * 128 + col];
        float w3 = W[(kk + 3) * 128 + col];
#pragma unroll
        for (int r = 0; r < 8; r++) {
            float4 v = *(const float4*)&xs[grp + 2 * r][kk];
            acc[r] += v.x * w0 + v.y * w1 + v.z * w2 + v.w * w3;
        }
    }
#pragma unroll
    for (int r = 0; r < 8; r++)
        out[(size_t)(n0 + grp + 2 * r) * 128 + col] = acc[r];
}

// ---------------------------------------------------------------------------
// GEMM2: [N,128] @ [128,32] -> [N,32].  32 nodes/block, 256 threads.
// ---------------------------------------------------------------------------
__global__ __launch_bounds__(256) void gemm2_kernel(const float* __restrict__ x,
                                                    const float* __restrict__ W,
                                                    float* __restrict__ out, int N) {
    __shared__ float xs[32][128];
    int n0  = blockIdx.x * 32;
    int col = threadIdx.x & 31;
    int grp = threadIdx.x >> 5;   // 0..7
    const float4* xv = (const float4*)(x + (size_t)n0 * 128);
    float4* xsv = (float4*)(&xs[0][0]);
    int limit = (N - n0) * 32;
    for (int i = threadIdx.x; i < 1024; i += 256) {
        float4 v = make_float4(0.f, 0.f, 0.f, 0.f);
        if (i < limit) v = xv[i];
        xsv[i] = v;
    }
    __syncthreads();

    float acc[4] = {0.f,0.f,0.f,0.f};
    for (int kk = 0; kk < 128; kk += 4) {
        float w0 = W[(kk + 0) * 32 + col];
        float w1 = W[(kk + 1) * 32 + col];
        float w2 = W[(kk + 2) * 32 + col];
        float w3 = W[(kk + 3) * 32 + col];
#pragma unroll
        for (int r = 0; r < 4; r++) {
            float4 v = *(const float4*)&xs[grp + 8 * r][kk];
            acc[r] += v.x * w0 + v.y * w1 + v.z * w2 + v.w * w3;
        }
    }
#pragma unroll
    for (int r = 0; r < 4; r++) {
        int n = n0 + grp + 8 * r;
        if (n < N) out[(size_t)n * 32 + col] = acc[r];
    }
}

// ---------------------------------------------------------------------------
// Attention logit dots
// ---------------------------------------------------------------------------
__global__ void dots1_kernel(const float* __restrict__ h1,
                             const float* __restrict__ a_src,
                             const float* __restrict__ a_dst,
                             float* __restrict__ es, float* __restrict__ ed,
                             int N4) {
    int t = blockIdx.x * 256 + threadIdx.x;
    if (t >= N4) return;
    int h = t & 3;
    const float4* hp = (const float4*)(h1 + (size_t)t * 32);
    const float4* ap = (const float4*)(a_src + h * 32);
    const float4* bp = (const float4*)(a_dst + h * 32);
    float s = 0.f, d = 0.f;
#pragma unroll
    for (int j = 0; j < 8; j++) {
        float4 v = hp[j], a = ap[j], b = bp[j];
        s += v.x * a.x + v.y * a.y + v.z * a.z + v.w * a.w;
        d += v.x * b.x + v.y * b.y + v.z * b.z + v.w * b.w;
    }
    es[t] = s; ed[t] = d;
}

__global__ void dots2_kernel(const float* __restrict__ h2,
                             const float* __restrict__ a_src,
                             const float* __restrict__ a_dst,
                             float* __restrict__ es, float* __restrict__ ed,
                             int N) {
    int t = blockIdx.x * 256 + threadIdx.x;
    if (t >= N) return;
    const float4* hp = (const float4*)(h2 + (size_t)t * 32);
    const float4* ap = (const float4*)a_src;
    const float4* bp = (const float4*)a_dst;
    float s = 0.f, d = 0.f;
#pragma unroll
    for (int j = 0; j < 8; j++) {
        float4 v = hp[j], a = ap[j], b = bp[j];
        s += v.x * a.x + v.y * a.y + v.z * a.z + v.w * a.w;
        d += v.x * b.x + v.y * b.y + v.z * b.z + v.w * b.w;
    }
    es[t] = s; ed[t] = d;
}

// ---------------------------------------------------------------------------
// Aggregation layer 1: one dst node per 128-thread block; edge loop unrolled
// x4 so 8 independent gathers are in flight (latency-bound loop -> MLP).
// ---------------------------------------------------------------------------
__global__ __launch_bounds__(128) void agg1_kernel(
        const float* __restrict__ h1, const float* __restrict__ es,
        const float* __restrict__ ed, const int* __restrict__ ptr,
        const int* __restrict__ csr_src, const float* __restrict__ b1,
        float* __restrict__ h1e) {
    int n = blockIdx.x;
    int c = threadIdx.x;          // 0..127
    int h = c >> 5;               // head
    float edl  = ed[n * 4 + h];
    int start = ptr[n], end = ptr[n + 1];
    float acc = 0.f, wsum = 0.f;
    int i = start;
    for (; i + 4 <= end; i += 4) {
        int s0 = csr_src[i + 0];
        int s1 = csr_src[i + 1];
        int s2 = csr_src[i + 2];
        int s3 = csr_src[i + 3];
        float e0 = es[s0 * 4 + h];
        float e1 = es[s1 * 4 + h];
        float e2 = es[s2 * 4 + h];
        float e3 = es[s3 * 4 + h];
        float g0 = h1[(size_t)s0 * 128 + c];
        float g1 = h1[(size_t)s1 * 128 + c];
        float g2 = h1[(size_t)s2 * 128 + c];
        float g3 = h1[(size_t)s3 * 128 + c];
        float l0 = e0 + edl; l0 = l0 > 0.f ? l0 : LRELU_SLOPE * l0;
        float l1 = e1 + edl; l1 = l1 > 0.f ? l1 : LRELU_SLOPE * l1;
        float l2 = e2 + edl; l2 = l2 > 0.f ? l2 : LRELU_SLOPE * l2;
        float l3 = e3 + edl; l3 = l3 > 0.f ? l3 : LRELU_SLOPE * l3;
        float w0 = __expf(l0), w1 = __expf(l1), w2 = __expf(l2), w3 = __expf(l3);
        wsum += (w0 + w1) + (w2 + w3);
        acc += w0 * g0 + w1 * g1 + w2 * g2 + w3 * g3;
    }
    for (; i < end; i++) {
        int s = csr_src[i];
        float l = es[s * 4 + h] + edl;
        l = l > 0.f ? l : LRELU_SLOPE * l;
        float w = __expf(l);
        wsum += w;
        acc += w * h1[(size_t)s * 128 + c];
    }
    float o = acc / wsum + b1[c];
    h1e[(size_t)n * 128 + c] = o > 0.f ? o : __expf(o) - 1.f;
}

// ---------------------------------------------------------------------------
// Aggregation layer 2: 4 nodes/block of 128 threads, unrolled x4.
// ---------------------------------------------------------------------------
__global__ __launch_bounds__(128) void agg2_kernel(
        const float* __restrict__ h2, const float* __restrict__ es,
        const float* __restrict__ ed, const int* __restrict__ ptr,
        const int* __restrict__ csr_src, const float* __restrict__ b2,
        float* __restrict__ out, int N) {
    int n = blockIdx.x * 4 + (threadIdx.x >> 5);
    if (n >= N) return;
    int c = threadIdx.x & 31;
    float edl = ed[n];
    int start = ptr[n], end = ptr[n + 1];
    float acc = 0.f, wsum = 0.f;
    int i = start;
    for (; i + 4 <= end; i += 4) {
        int s0 = csr_src[i + 0];
        int s1 = csr_src[i + 1];
        int s2 = csr_src[i + 2];
        int s3 = csr_src[i + 3];
        float e0 = es[s0];
        float e1 = es[s1];
        float e2 = es[s2];
        float e3 = es[s3];
        float g0 = h2[(size_t)s0 * 32 + c];
        float g1 = h2[(size_t)s1 * 32 + c];
        float g2 = h2[(size_t)s2 * 32 + c];
        float g3 = h2[(size_t)s3 * 32 + c];
        float l0 = e0 + edl; l0 = l0 > 0.f ? l0 : LRELU_SLOPE * l0;
        float l1 = e1 + edl; l1 = l1 > 0.f ? l1 : LRELU_SLOPE * l1;
        float l2 = e2 + edl; l2 = l2 > 0.f ? l2 : LRELU_SLOPE * l2;
        float l3 = e3 + edl; l3 = l3 > 0.f ? l3 : LRELU_SLOPE * l3;
        float w0 = __expf(l0), w1 = __expf(l1), w2 = __expf(l2), w3 = __expf(l3);
        wsum += (w0 + w1) + (w2 + w3);
        acc += w0 * g0 + w1 * g1 + w2 * g2 + w3 * g3;
    }
    for (; i < end; i++) {
        int s = csr_src[i];
        float l = es[s] + edl;
        l = l > 0.f ? l : LRELU_SLOPE * l;
        float w = __expf(l);
        wsum += w;
        acc += w * h2[(size_t)s * 32 + c];
    }
    out[(size_t)n * 32 + c] = acc / wsum + b2[c];
}

// ---------------------------------------------------------------------------
extern "C" void kernel_launch(void* const* d_in, const int* in_sizes, int n_in,
                              void* d_out, int out_size, void* d_ws, size_t ws_size,
                              hipStream_t stream) {
    const float* x      = (const float*)d_in[0];
    const int*   ei     = (const int*)  d_in[1];
    const float* W1     = (const float*)d_in[2];
    const float* a_src1 = (const float*)d_in[3];
    const float* a_dst1 = (const float*)d_in[4];
    const float* b1     = (const float*)d_in[5];
    const float* W2     = (const float*)d_in[6];
    const float* a_src2 = (const float*)d_in[7];
    const float* a_dst2 = (const float*)d_in[8];
    const float* b2     = (const float*)d_in[9];
    float* outp = (float*)d_out;

    const int N = in_sizes[0] / 128;   // 50000
    const int E = in_sizes[1] / 2;     // 800000
    const int Etot = E + N;            // with self-loops

    const int* src = ei;
    const int* dst = ei + E;

    // workspace layout (bytes) — kept within the footprint proven in R1
    char* w = (char*)d_ws;
    float* h1raw   = (float*)(w + 0);               // N*128*4 = 25,600,000
    float* h1e     = (float*)(w + 25600000);        // N*128*4
    float* h2      = (float*)(w + 51200000);        // N*32*4  =  6,400,000
    float* es1     = (float*)(w + 57600000);        // N*4*4
    float* ed1     = (float*)(w + 58400000);        // N*4*4
    float* es2     = (float*)(w + 59200000);        // N*4
    float* ed2     = (float*)(w + 59400000);        // N*4
    int*   deg     = (int*)  (w + 59600000);        // N*4 (reused as scatter cursor)
    int*   ptr     = (int*)  (w + 59800000);        // (N+1)*4, padded
    int*   bsum    = (int*)  (w + 60000032);        // 256*4
    int*   csr_src = (int*)  (w + 60001056);        // Etot*4 = 3,400,000 -> ends 63,401,056

    const int nbA = (N + 1023) / 1024;   // 49

    // --- CSR build (shared by both layers) ---
    zero_int_kernel<<<(N + 255) / 256, 256, 0, stream>>>(deg, N);
    degree_kernel<<<(Etot + 255) / 256, 256, 0, stream>>>(dst, E, N, deg);
    scanA_kernel<<<nbA, 1024, 0, stream>>>(deg, ptr, bsum, N);
    scanB_kernel<<<1, 256, 0, stream>>>(bsum, nbA);
    scanC_kernel<<<(N + 255) / 256, 256, 0, stream>>>(ptr, deg, bsum, N, Etot);
    scatter_kernel<<<(Etot + 255) / 256, 256, 0, stream>>>(src, dst, E, N, deg, csr_src);

    // --- Layer 1 ---
    gemm1_kernel<<<N / 16, 256, 0, stream>>>(x, W1, h1raw);
    dots1_kernel<<<(N * 4 + 255) / 256, 256, 0, stream>>>(h1raw, a_src1, a_dst1, es1, ed1, N * 4);
    agg1_kernel<<<N, 128, 0, stream>>>(h1raw, es1, ed1, ptr, csr_src, b1, h1e);

    // --- Layer 2 ---
    gemm2_kernel<<<(N + 31) / 32, 256, 0, stream>>>(h1e, W2, h2, N);
    dots2_kernel<<<(N + 255) / 256, 256, 0, stream>>>(h2, a_src2, a_dst2, es2, ed2, N);
    agg2_kernel<<<(N + 3) / 4, 128, 0, stream>>>(h2, es2, ed2, ptr, csr_src, b2, outp, N);
}

// Round 3
// 357.784 us; speedup vs baseline: 1.4560x; 1.0483x over previous
//
#include <hip/hip_runtime.h>
#include <hip/hip_bf16.h>

#define LRELU_SLOPE 0.2f

typedef __attribute__((ext_vector_type(8))) short short8;
typedef __attribute__((ext_vector_type(4))) float float4v;

// bf16 <-> fp32 helpers (raw ushort storage; avoids hip_bf16.h ABI variance)
__device__ inline float b2f(unsigned short u) {
    union { unsigned int i; float f; } v; v.i = ((unsigned int)u) << 16; return v.f;
}
__device__ inline unsigned short f2b(float f) {
    union { float f; unsigned int i; } v; v.f = f;
    unsigned int x = v.i;
    unsigned int r = x + 0x7fffu + ((x >> 16) & 1u);   // round-to-nearest-even
    return (unsigned short)(r >> 16);
}

// ---------------------------------------------------------------------------
// CSR build: degree count -> two-level parallel scan -> scatter
// ---------------------------------------------------------------------------
__global__ void zero_int_kernel(int* __restrict__ p, int n) {
    int i = blockIdx.x * 256 + threadIdx.x;
    if (i < n) p[i] = 0;
}

__global__ void degree_kernel(const int* __restrict__ dst, int E, int N,
                              int* __restrict__ deg) {
    int i = blockIdx.x * 256 + threadIdx.x;
    int total = E + N;
    if (i >= total) return;
    int d = (i < E) ? dst[i] : (i - E);   // self-loops appended
    atomicAdd(&deg[d], 1);
}

__global__ __launch_bounds__(1024) void scanA_kernel(const int* __restrict__ deg,
                                                     int* __restrict__ ptr,
                                                     int* __restrict__ bsum, int N) {
    __shared__ int tile[1024];
    int i = blockIdx.x * 1024 + threadIdx.x;
    int v = (i < N) ? deg[i] : 0;
    tile[threadIdx.x] = v;
    __syncthreads();
    for (int off = 1; off < 1024; off <<= 1) {
        int t = (threadIdx.x >= (unsigned)off) ? tile[threadIdx.x - off] : 0;
        __syncthreads();
        tile[threadIdx.x] += t;
        __syncthreads();
    }
    int incl = tile[threadIdx.x];
    if (i < N) ptr[i] = incl - v;
    if (threadIdx.x == 1023) bsum[blockIdx.x] = incl;
}

__global__ __launch_bounds__(256) void scanB_kernel(int* __restrict__ bsum, int nb) {
    __shared__ int tile[256];
    int v = (threadIdx.x < (unsigned)nb) ? bsum[threadIdx.x] : 0;
    tile[threadIdx.x] = v;
    __syncthreads();
    for (int off = 1; off < 256; off <<= 1) {
        int t = (threadIdx.x >= (unsigned)off) ? tile[threadIdx.x - off] : 0;
        __syncthreads();
        tile[threadIdx.x] += t;
        __syncthreads();
    }
    if (threadIdx.x < (unsigned)nb) bsum[threadIdx.x] = tile[threadIdx.x] - v;
}

__global__ void scanC_kernel(int* __restrict__ ptr, int* __restrict__ cursor,
                             const int* __restrict__ boff, int N, int Etot) {
    int i = blockIdx.x * 256 + threadIdx.x;
    if (i == 0) ptr[N] = Etot;
    if (i >= N) return;
    int p = ptr[i] + boff[i >> 10];
    ptr[i] = p;
    cursor[i] = p;
}

__global__ void scatter_kernel(const int* __restrict__ src,
                               const int* __restrict__ dst, int E, int N,
                               int* __restrict__ cursor,
                               int* __restrict__ csr_src) {
    int i = blockIdx.x * 256 + threadIdx.x;
    int total = E + N;
    if (i >= total) return;
    int s, d;
    if (i < E) { s = src[i]; d = dst[i]; }
    else       { s = d = i - E; }
    int pos = atomicAdd(&cursor[d], 1);
    csr_src[pos] = s;
}

// ---------------------------------------------------------------------------
// GEMM1 (MFMA bf16): h1b[N][128] = bf16( bf16(x)[N,128] @ bf16(W1)[128,128] )
// Block: 256 thr = 4 waves; 64 rows/block; wave w handles rows w*16..w*16+15,
// loops over 8 col-tiles of 16; K = 128 = 4 chunks of 32.
// Layouts (guide-verified): A[m=lane&15][k=quad*8+j]; B[k=quad*8+j][n=lane&15];
// D: row=quad*4+reg, col=lane&15.
// ---------------------------------------------------------------------------
__global__ __launch_bounds__(256) void gemm1_mfma_kernel(
        const float* __restrict__ x, const float* __restrict__ W1,
        unsigned short* __restrict__ h1b, int N) {
    __shared__ unsigned short xs[64][136];   // [row][k], pad 136 -> 272 B row (16B-aligned)
    __shared__ unsigned short wt[128][136];  // [n][k] = W1[k][n]
    int tid = threadIdx.x;
    int n0 = blockIdx.x * 64;

    // stage Wt (transpose + cast). reads coalesced over n.
    for (int i = tid; i < 128 * 128; i += 256) {
        int k = i >> 7, n = i & 127;
        wt[n][k] = f2b(W1[i]);
    }
    // stage x tile (cast). rows clamped for last block.
    for (int i = tid; i < 64 * 128; i += 256) {
        int r = i >> 7, k = i & 127;
        int row = n0 + r; if (row >= N) row = N - 1;
        xs[r][k] = f2b(x[(size_t)row * 128 + k]);
    }
    __syncthreads();

    int wave = tid >> 6;
    int lane = tid & 63;
    int lrow = lane & 15;
    int quad = lane >> 4;

    // A fragments: 4 k-chunks, reused across all col-tiles
    short8 afr[4];
#pragma unroll
    for (int kc = 0; kc < 4; kc++)
        afr[kc] = *(const short8*)&xs[wave * 16 + lrow][kc * 32 + quad * 8];

#pragma unroll
    for (int ct = 0; ct < 8; ct++) {
        float4v acc = {0.f, 0.f, 0.f, 0.f};
#pragma unroll
        for (int kc = 0; kc < 4; kc++) {
            short8 bfr = *(const short8*)&wt[ct * 16 + lrow][kc * 32 + quad * 8];
            acc = __builtin_amdgcn_mfma_f32_16x16x32_bf16(afr[kc], bfr, acc, 0, 0, 0);
        }
#pragma unroll
        for (int r = 0; r < 4; r++) {
            int grow = n0 + wave * 16 + quad * 4 + r;
            if (grow < N)
                h1b[grow * 128 + ct * 16 + lrow] = f2b(acc[r]);
        }
    }
}

// ---------------------------------------------------------------------------
// Attention logit dots, layer 1 (bf16 h): row t = n*4+h starts at t*32
// ---------------------------------------------------------------------------
__global__ void dots1_kernel(const unsigned short* __restrict__ h1b,
                             const float* __restrict__ a_src,
                             const float* __restrict__ a_dst,
                             float* __restrict__ es, float* __restrict__ ed,
                             int N4) {
    int t = blockIdx.x * 256 + threadIdx.x;
    if (t >= N4) return;
    int h = t & 3;
    const unsigned short* hp = h1b + (size_t)t * 32;
    const float* ap = a_src + h * 32;
    const float* bp = a_dst + h * 32;
    float s = 0.f, d = 0.f;
#pragma unroll
    for (int j = 0; j < 32; j++) {
        float v = b2f(hp[j]);
        s += v * ap[j]; d += v * bp[j];
    }
    es[t] = s; ed[t] = d;
}

__global__ void dots2_kernel(const float* __restrict__ h2,
                             const float* __restrict__ a_src,
                             const float* __restrict__ a_dst,
                             float* __restrict__ es, float* __restrict__ ed,
                             int N) {
    int t = blockIdx.x * 256 + threadIdx.x;
    if (t >= N) return;
    const float4* hp = (const float4*)(h2 + (size_t)t * 32);
    const float4* ap = (const float4*)a_src;
    const float4* bp = (const float4*)a_dst;
    float s = 0.f, d = 0.f;
#pragma unroll
    for (int j = 0; j < 8; j++) {
        float4 v = hp[j], a = ap[j], b = bp[j];
        s += v.x * a.x + v.y * a.y + v.z * a.z + v.w * a.w;
        d += v.x * b.x + v.y * b.y + v.z * b.z + v.w * b.w;
    }
    es[t] = s; ed[t] = d;
}

// ---------------------------------------------------------------------------
// Aggregation layer 1: one dst node per 128-thread block; bf16 gathers,
// unrolled x4 (8 independent gathers in flight). Fp32 accumulate.
// Epilogue: ELU -> bf16 h1e (layer-2 input).
// ---------------------------------------------------------------------------
__global__ __launch_bounds__(128) void agg1_kernel(
        const unsigned short* __restrict__ h1b, const float* __restrict__ es,
        const float* __restrict__ ed, const int* __restrict__ ptr,
        const int* __restrict__ csr_src, const float* __restrict__ b1,
        unsigned short* __restrict__ h1e) {
    int n = blockIdx.x;
    int c = threadIdx.x;
    int h = c >> 5;
    float edl = ed[(n << 2) + h];
    int start = ptr[n], end = ptr[n + 1];
    float acc = 0.f, wsum = 0.f;
    int i = start;
    for (; i + 4 <= end; i += 4) {
        int s0 = csr_src[i + 0];
        int s1 = csr_src[i + 1];
        int s2 = csr_src[i + 2];
        int s3 = csr_src[i + 3];
        float e0 = es[(s0 << 2) + h];
        float e1 = es[(s1 << 2) + h];
        float e2 = es[(s2 << 2) + h];
        float e3 = es[(s3 << 2) + h];
        float g0 = b2f(h1b[(s0 << 7) + c]);
        float g1 = b2f(h1b[(s1 << 7) + c]);
        float g2 = b2f(h1b[(s2 << 7) + c]);
        float g3 = b2f(h1b[(s3 << 7) + c]);
        float l0 = e0 + edl; l0 = l0 > 0.f ? l0 : LRELU_SLOPE * l0;
        float l1 = e1 + edl; l1 = l1 > 0.f ? l1 : LRELU_SLOPE * l1;
        float l2 = e2 + edl; l2 = l2 > 0.f ? l2 : LRELU_SLOPE * l2;
        float l3 = e3 + edl; l3 = l3 > 0.f ? l3 : LRELU_SLOPE * l3;
        float w0 = __expf(l0), w1 = __expf(l1), w2 = __expf(l2), w3 = __expf(l3);
        wsum += (w0 + w1) + (w2 + w3);
        acc += w0 * g0 + w1 * g1 + w2 * g2 + w3 * g3;
    }
    for (; i < end; i++) {
        int s = csr_src[i];
        float l = es[(s << 2) + h] + edl;
        l = l > 0.f ? l : LRELU_SLOPE * l;
        float w = __expf(l);
        wsum += w;
        acc += w * b2f(h1b[(s << 7) + c]);
    }
    float o = acc / wsum + b1[c];
    o = o > 0.f ? o : __expf(o) - 1.f;
    h1e[(n << 7) + c] = f2b(o);
}

// ---------------------------------------------------------------------------
// GEMM2: bf16 [N,128] @ fp32 [128,32] -> fp32 [N,32].  32 nodes/block.
// ---------------------------------------------------------------------------
__global__ __launch_bounds__(256) void gemm2_kernel(const unsigned short* __restrict__ xb,
                                                    const float* __restrict__ W,
                                                    float* __restrict__ out, int N) {
    __shared__ float xs[32][128];
    int tid = threadIdx.x;
    int n0 = blockIdx.x * 32;
    int col = tid & 31;
    int grp = tid >> 5;
    int limit = (N - n0) * 128;
    const unsigned short* xp = xb + (size_t)n0 * 128;
    float* xsf = &xs[0][0];
    for (int i = tid; i < 4096; i += 256) {
        float v = 0.f;
        if (i < limit) v = b2f(xp[i]);
        xsf[i] = v;
    }
    __syncthreads();

    float acc[4] = {0.f, 0.f, 0.f, 0.f};
    for (int kk = 0; kk < 128; kk += 4) {
        float w0 = W[(kk + 0) * 32 + col];
        float w1 = W[(kk + 1) * 32 + col];
        float w2 = W[(kk + 2) * 32 + col];
        float w3 = W[(kk + 3) * 32 + col];
#pragma unroll
        for (int r = 0; r < 4; r++) {
            float4 v = *(const float4*)&xs[grp + 8 * r][kk];
            acc[r] += v.x * w0 + v.y * w1 + v.z * w2 + v.w * w3;
        }
    }
#pragma unroll
    for (int r = 0; r < 4; r++) {
        int n = n0 + grp + 8 * r;
        if (n < N) out[(size_t)n * 32 + col] = acc[r];
    }
}

// ---------------------------------------------------------------------------
// Aggregation layer 2: 4 nodes/block of 128 threads, unrolled x4, fp32 h2.
// ---------------------------------------------------------------------------
__global__ __launch_bounds__(128) void agg2_kernel(
        const float* __restrict__ h2, const float* __restrict__ es,
        const float* __restrict__ ed, const int* __restrict__ ptr,
        const int* __restrict__ csr_src, const float* __restrict__ b2,
        float* __restrict__ out, int N) {
    int n = blockIdx.x * 4 + (threadIdx.x >> 5);
    if (n >= N) return;
    int c = threadIdx.x & 31;
    float edl = ed[n];
    int start = ptr[n], end = ptr[n + 1];
    float acc = 0.f, wsum = 0.f;
    int i = start;
    for (; i + 4 <= end; i += 4) {
        int s0 = csr_src[i + 0];
        int s1 = csr_src[i + 1];
        int s2 = csr_src[i + 2];
        int s3 = csr_src[i + 3];
        float e0 = es[s0];
        float e1 = es[s1];
        float e2 = es[s2];
        float e3 = es[s3];
        float g0 = h2[(s0 << 5) + c];
        float g1 = h2[(s1 << 5) + c];
        float g2 = h2[(s2 << 5) + c];
        float g3 = h2[(s3 << 5) + c];
        float l0 = e0 + edl; l0 = l0 > 0.f ? l0 : LRELU_SLOPE * l0;
        float l1 = e1 + edl; l1 = l1 > 0.f ? l1 : LRELU_SLOPE * l1;
        float l2 = e2 + edl; l2 = l2 > 0.f ? l2 : LRELU_SLOPE * l2;
        float l3 = e3 + edl; l3 = l3 > 0.f ? l3 : LRELU_SLOPE * l3;
        float w0 = __expf(l0), w1 = __expf(l1), w2 = __expf(l2), w3 = __expf(l3);
        wsum += (w0 + w1) + (w2 + w3);
        acc += w0 * g0 + w1 * g1 + w2 * g2 + w3 * g3;
    }
    for (; i < end; i++) {
        int s = csr_src[i];
        float l = es[s] + edl;
        l = l > 0.f ? l : LRELU_SLOPE * l;
        float w = __expf(l);
        wsum += w;
        acc += w * h2[(s << 5) + c];
    }
    out[(size_t)n * 32 + c] = acc / wsum + b2[c];
}

// ---------------------------------------------------------------------------
extern "C" void kernel_launch(void* const* d_in, const int* in_sizes, int n_in,
                              void* d_out, int out_size, void* d_ws, size_t ws_size,
                              hipStream_t stream) {
    const float* x      = (const float*)d_in[0];
    const int*   ei     = (const int*)  d_in[1];
    const float* W1     = (const float*)d_in[2];
    const float* a_src1 = (const float*)d_in[3];
    const float* a_dst1 = (const float*)d_in[4];
    const float* b1     = (const float*)d_in[5];
    const float* W2     = (const float*)d_in[6];
    const float* a_src2 = (const float*)d_in[7];
    const float* a_dst2 = (const float*)d_in[8];
    const float* b2     = (const float*)d_in[9];
    float* outp = (float*)d_out;

    const int N = in_sizes[0] / 128;   // 50000
    const int E = in_sizes[1] / 2;     // 800000
    const int Etot = E + N;

    const int* src = ei;
    const int* dst = ei + E;

    // workspace layout (bytes); total ~37.8 MB (< R2's proven 63.4 MB)
    char* w = (char*)d_ws;
    unsigned short* h1b = (unsigned short*)(w + 0);          // N*128*2 = 12,800,000
    unsigned short* h1e = (unsigned short*)(w + 12800000);   // N*128*2
    float* h2   = (float*)(w + 25600000);                    // N*32*4 = 6,400,000
    float* es1  = (float*)(w + 32000000);                    // N*4*4
    float* ed1  = (float*)(w + 32800000);                    // N*4*4
    float* es2  = (float*)(w + 33600000);                    // N*4
    float* ed2  = (float*)(w + 33800000);                    // N*4
    int*   deg  = (int*)  (w + 34000000);                    // N*4 (reused as cursor)
    int*   ptr  = (int*)  (w + 34200000);                    // (N+1)*4 (+pad)
    int*   bsum = (int*)  (w + 34400032);                    // 256*4
    int*   csr_src = (int*)(w + 34401056);                   // Etot*4 -> ends 37,801,056

    const int nbA = (N + 1023) / 1024;   // 49

    // --- CSR build (shared by both layers) ---
    zero_int_kernel<<<(N + 255) / 256, 256, 0, stream>>>(deg, N);
    degree_kernel<<<(Etot + 255) / 256, 256, 0, stream>>>(dst, E, N, deg);
    scanA_kernel<<<nbA, 1024, 0, stream>>>(deg, ptr, bsum, N);
    scanB_kernel<<<1, 256, 0, stream>>>(bsum, nbA);
    scanC_kernel<<<(N + 255) / 256, 256, 0, stream>>>(ptr, deg, bsum, N, Etot);
    scatter_kernel<<<(Etot + 255) / 256, 256, 0, stream>>>(src, dst, E, N, deg, csr_src);

    // --- Layer 1 ---
    gemm1_mfma_kernel<<<(N + 63) / 64, 256, 0, stream>>>(x, W1, h1b, N);
    dots1_kernel<<<(N * 4 + 255) / 256, 256, 0, stream>>>(h1b, a_src1, a_dst1, es1, ed1, N * 4);
    agg1_kernel<<<N, 128, 0, stream>>>(h1b, es1, ed1, ptr, csr_src, b1, h1e);

    // --- Layer 2 ---
    gemm2_kernel<<<(N + 31) / 32, 256, 0, stream>>>(h1e, W2, h2, N);
    dots2_kernel<<<(N + 255) / 256, 256, 0, stream>>>(h2, a_src2, a_dst2, es2, ed2, N);
    agg2_kernel<<<(N + 3) / 4, 128, 0, stream>>>(h2, es2, ed2, ptr, csr_src, b2, outp, N);
}

// Round 4
// 305.205 us; speedup vs baseline: 1.7068x; 1.1723x over previous
//
#include <hip/hip_runtime.h>
#include <hip/hip_bf16.h>

#define LRELU_SLOPE 0.2f

typedef __attribute__((ext_vector_type(8))) short short8;
typedef __attribute__((ext_vector_type(4))) float float4v;

// bf16 <-> fp32 helpers (raw ushort storage)
__device__ inline float b2f(unsigned short u) {
    union { unsigned int i; float f; } v; v.i = ((unsigned int)u) << 16; return v.f;
}
__device__ inline unsigned short f2b(float f) {
    union { float f; unsigned int i; } v; v.f = f;
    unsigned int x = v.i;
    unsigned int r = x + 0x7fffu + ((x >> 16) & 1u);   // round-to-nearest-even
    return (unsigned short)(r >> 16);
}

// ---------------------------------------------------------------------------
// CSR build: degree count -> two-level parallel scan -> scatter
// ---------------------------------------------------------------------------
__global__ void zero_int_kernel(int* __restrict__ p, int n) {
    int i = blockIdx.x * 256 + threadIdx.x;
    if (i < n) p[i] = 0;
}

__global__ void degree_kernel(const int* __restrict__ dst, int E, int N,
                              int* __restrict__ deg) {
    int i = blockIdx.x * 256 + threadIdx.x;
    int total = E + N;
    if (i >= total) return;
    int d = (i < E) ? dst[i] : (i - E);   // self-loops appended
    atomicAdd(&deg[d], 1);
}

__global__ __launch_bounds__(1024) void scanA_kernel(const int* __restrict__ deg,
                                                     int* __restrict__ ptr,
                                                     int* __restrict__ bsum, int N) {
    __shared__ int tile[1024];
    int i = blockIdx.x * 1024 + threadIdx.x;
    int v = (i < N) ? deg[i] : 0;
    tile[threadIdx.x] = v;
    __syncthreads();
    for (int off = 1; off < 1024; off <<= 1) {
        int t = (threadIdx.x >= (unsigned)off) ? tile[threadIdx.x - off] : 0;
        __syncthreads();
        tile[threadIdx.x] += t;
        __syncthreads();
    }
    int incl = tile[threadIdx.x];
    if (i < N) ptr[i] = incl - v;
    if (threadIdx.x == 1023) bsum[blockIdx.x] = incl;
}

__global__ __launch_bounds__(256) void scanB_kernel(int* __restrict__ bsum, int nb) {
    __shared__ int tile[256];
    int v = (threadIdx.x < (unsigned)nb) ? bsum[threadIdx.x] : 0;
    tile[threadIdx.x] = v;
    __syncthreads();
    for (int off = 1; off < 256; off <<= 1) {
        int t = (threadIdx.x >= (unsigned)off) ? tile[threadIdx.x - off] : 0;
        __syncthreads();
        tile[threadIdx.x] += t;
        __syncthreads();
    }
    if (threadIdx.x < (unsigned)nb) bsum[threadIdx.x] = tile[threadIdx.x] - v;
}

__global__ void scanC_kernel(int* __restrict__ ptr, int* __restrict__ cursor,
                             const int* __restrict__ boff, int N, int Etot) {
    int i = blockIdx.x * 256 + threadIdx.x;
    if (i == 0) ptr[N] = Etot;
    if (i >= N) return;
    int p = ptr[i] + boff[i >> 10];
    ptr[i] = p;
    cursor[i] = p;
}

__global__ void scatter_kernel(const int* __restrict__ src,
                               const int* __restrict__ dst, int E, int N,
                               int* __restrict__ cursor,
                               int* __restrict__ csr_src) {
    int i = blockIdx.x * 256 + threadIdx.x;
    int total = E + N;
    if (i >= total) return;
    int s, d;
    if (i < E) { s = src[i]; d = dst[i]; }
    else       { s = d = i - E; }
    int pos = atomicAdd(&cursor[d], 1);
    csr_src[pos] = s;
}

// ---------------------------------------------------------------------------
// GEMM1 (MFMA bf16): h1b[N][128] = bf16( bf16(x)[N,128] @ bf16(W1)[128,128] )
// ---------------------------------------------------------------------------
__global__ __launch_bounds__(256) void gemm1_mfma_kernel(
        const float* __restrict__ x, const float* __restrict__ W1,
        unsigned short* __restrict__ h1b, int N) {
    __shared__ unsigned short xs[64][136];   // pad 136 -> 272 B row (16B-aligned)
    __shared__ unsigned short wt[128][136];  // [n][k] = W1[k][n]
    int tid = threadIdx.x;
    int n0 = blockIdx.x * 64;

    for (int i = tid; i < 128 * 128; i += 256) {
        int k = i >> 7, n = i & 127;
        wt[n][k] = f2b(W1[i]);
    }
    for (int i = tid; i < 64 * 128; i += 256) {
        int r = i >> 7, k = i & 127;
        int row = n0 + r; if (row >= N) row = N - 1;
        xs[r][k] = f2b(x[(size_t)row * 128 + k]);
    }
    __syncthreads();

    int wave = tid >> 6;
    int lane = tid & 63;
    int lrow = lane & 15;
    int quad = lane >> 4;

    short8 afr[4];
#pragma unroll
    for (int kc = 0; kc < 4; kc++)
        afr[kc] = *(const short8*)&xs[wave * 16 + lrow][kc * 32 + quad * 8];

#pragma unroll
    for (int ct = 0; ct < 8; ct++) {
        float4v acc = {0.f, 0.f, 0.f, 0.f};
#pragma unroll
        for (int kc = 0; kc < 4; kc++) {
            short8 bfr = *(const short8*)&wt[ct * 16 + lrow][kc * 32 + quad * 8];
            acc = __builtin_amdgcn_mfma_f32_16x16x32_bf16(afr[kc], bfr, acc, 0, 0, 0);
        }
#pragma unroll
        for (int r = 0; r < 4; r++) {
            int grow = n0 + wave * 16 + quad * 4 + r;
            if (grow < N)
                h1b[grow * 128 + ct * 16 + lrow] = f2b(acc[r]);
        }
    }
}

// ---------------------------------------------------------------------------
// GEMM2 (MFMA bf16): h2[N][32] = fp32( h1e[N,128]bf16 @ bf16(W2)[128,32] )
// Same structure as gemm1; 2 col-tiles. VGPR-light (fixes R3's 256-VGPR cliff).
// ---------------------------------------------------------------------------
__global__ __launch_bounds__(256) void gemm2_mfma_kernel(
        const unsigned short* __restrict__ h1e, const float* __restrict__ W2,
        float* __restrict__ h2, int N) {
    __shared__ unsigned short xs[64][136];
    __shared__ unsigned short wt[32][136];
    int tid = threadIdx.x;
    int n0 = blockIdx.x * 64;

    // stage W2^T: wt[n][k] = bf16(W2[k][n]); reads coalesced over n
    for (int i = tid; i < 128 * 32; i += 256) {
        int k = i >> 5, n = i & 31;
        wt[n][k] = f2b(W2[i]);
    }
    // stage x tile: bf16 copy in 4-byte chunks (64 uints per row)
    {
        const unsigned int* srcp = (const unsigned int*)(h1e + (size_t)n0 * 128);
        int rows = (N - n0) < 64 ? (N - n0) : 64;
        int maxu = rows * 64;
        for (int i = tid; i < 4096; i += 256) {
            unsigned int v = (i < maxu) ? srcp[i] : 0u;
            int r = i >> 6, cp = (i & 63) << 1;
            *(unsigned int*)&xs[r][cp] = v;
        }
    }
    __syncthreads();

    int wave = tid >> 6;
    int lane = tid & 63;
    int lrow = lane & 15;
    int quad = lane >> 4;

    short8 afr[4];
#pragma unroll
    for (int kc = 0; kc < 4; kc++)
        afr[kc] = *(const short8*)&xs[wave * 16 + lrow][kc * 32 + quad * 8];

#pragma unroll
    for (int ct = 0; ct < 2; ct++) {
        float4v acc = {0.f, 0.f, 0.f, 0.f};
#pragma unroll
        for (int kc = 0; kc < 4; kc++) {
            short8 bfr = *(const short8*)&wt[ct * 16 + lrow][kc * 32 + quad * 8];
            acc = __builtin_amdgcn_mfma_f32_16x16x32_bf16(afr[kc], bfr, acc, 0, 0, 0);
        }
#pragma unroll
        for (int r = 0; r < 4; r++) {
            int grow = n0 + wave * 16 + quad * 4 + r;
            if (grow < N)
                h2[(size_t)grow * 32 + ct * 16 + lrow] = acc[r];
        }
    }
}

// ---------------------------------------------------------------------------
// Attention logit dots, layer 1 (bf16 h): row t = n*4+h starts at t*32
// ---------------------------------------------------------------------------
__global__ void dots1_kernel(const unsigned short* __restrict__ h1b,
                             const float* __restrict__ a_src,
                             const float* __restrict__ a_dst,
                             float* __restrict__ es, float* __restrict__ ed,
                             int N4) {
    int t = blockIdx.x * 256 + threadIdx.x;
    if (t >= N4) return;
    int h = t & 3;
    const unsigned int* hp = (const unsigned int*)(h1b + (size_t)t * 32);
    const float* ap = a_src + h * 32;
    const float* bp = a_dst + h * 32;
    float s = 0.f, d = 0.f;
#pragma unroll
    for (int j = 0; j < 16; j++) {
        unsigned int u = hp[j];
        float v0 = b2f((unsigned short)(u & 0xffffu));
        float v1 = b2f((unsigned short)(u >> 16));
        s += v0 * ap[2 * j] + v1 * ap[2 * j + 1];
        d += v0 * bp[2 * j] + v1 * bp[2 * j + 1];
    }
    es[t] = s; ed[t] = d;
}

__global__ void dots2_kernel(const float* __restrict__ h2,
                             const float* __restrict__ a_src,
                             const float* __restrict__ a_dst,
                             float* __restrict__ es, float* __restrict__ ed,
                             int N) {
    int t = blockIdx.x * 256 + threadIdx.x;
    if (t >= N) return;
    const float4* hp = (const float4*)(h2 + (size_t)t * 32);
    const float4* ap = (const float4*)a_src;
    const float4* bp = (const float4*)a_dst;
    float s = 0.f, d = 0.f;
#pragma unroll
    for (int j = 0; j < 8; j++) {
        float4 v = hp[j], a = ap[j], b = bp[j];
        s += v.x * a.x + v.y * a.y + v.z * a.z + v.w * a.w;
        d += v.x * b.x + v.y * b.y + v.z * b.z + v.w * b.w;
    }
    es[t] = s; ed[t] = d;
}

// ---------------------------------------------------------------------------
// Aggregation layer 1: one dst node per 128-thread block; bf16 gathers,
// unrolled x4. Fp32 accumulate. Epilogue: ELU -> bf16 h1e.
// ---------------------------------------------------------------------------
__global__ __launch_bounds__(128) void agg1_kernel(
        const unsigned short* __restrict__ h1b, const float* __restrict__ es,
        const float* __restrict__ ed, const int* __restrict__ ptr,
        const int* __restrict__ csr_src, const float* __restrict__ b1,
        unsigned short* __restrict__ h1e) {
    int n = blockIdx.x;
    int c = threadIdx.x;
    int h = c >> 5;
    float edl = ed[(n << 2) + h];
    int start = ptr[n], end = ptr[n + 1];
    float acc = 0.f, wsum = 0.f;
    int i = start;
    for (; i + 4 <= end; i += 4) {
        int s0 = csr_src[i + 0];
        int s1 = csr_src[i + 1];
        int s2 = csr_src[i + 2];
        int s3 = csr_src[i + 3];
        float e0 = es[(s0 << 2) + h];
        float e1 = es[(s1 << 2) + h];
        float e2 = es[(s2 << 2) + h];
        float e3 = es[(s3 << 2) + h];
        float g0 = b2f(h1b[(s0 << 7) + c]);
        float g1 = b2f(h1b[(s1 << 7) + c]);
        float g2 = b2f(h1b[(s2 << 7) + c]);
        float g3 = b2f(h1b[(s3 << 7) + c]);
        float l0 = e0 + edl; l0 = l0 > 0.f ? l0 : LRELU_SLOPE * l0;
        float l1 = e1 + edl; l1 = l1 > 0.f ? l1 : LRELU_SLOPE * l1;
        float l2 = e2 + edl; l2 = l2 > 0.f ? l2 : LRELU_SLOPE * l2;
        float l3 = e3 + edl; l3 = l3 > 0.f ? l3 : LRELU_SLOPE * l3;
        float w0 = __expf(l0), w1 = __expf(l1), w2 = __expf(l2), w3 = __expf(l3);
        wsum += (w0 + w1) + (w2 + w3);
        acc += w0 * g0 + w1 * g1 + w2 * g2 + w3 * g3;
    }
    for (; i < end; i++) {
        int s = csr_src[i];
        float l = es[(s << 2) + h] + edl;
        l = l > 0.f ? l : LRELU_SLOPE * l;
        float w = __expf(l);
        wsum += w;
        acc += w * b2f(h1b[(s << 7) + c]);
    }
    float o = acc / wsum + b1[c];
    o = o > 0.f ? o : __expf(o) - 1.f;
    h1e[(n << 7) + c] = f2b(o);
}

// ---------------------------------------------------------------------------
// Aggregation layer 2: 4 nodes/block of 128 threads, unrolled x4, fp32 h2.
// ---------------------------------------------------------------------------
__global__ __launch_bounds__(128) void agg2_kernel(
        const float* __restrict__ h2, const float* __restrict__ es,
        const float* __restrict__ ed, const int* __restrict__ ptr,
        const int* __restrict__ csr_src, const float* __restrict__ b2,
        float* __restrict__ out, int N) {
    int n = blockIdx.x * 4 + (threadIdx.x >> 5);
    if (n >= N) return;
    int c = threadIdx.x & 31;
    float edl = ed[n];
    int start = ptr[n], end = ptr[n + 1];
    float acc = 0.f, wsum = 0.f;
    int i = start;
    for (; i + 4 <= end; i += 4) {
        int s0 = csr_src[i + 0];
        int s1 = csr_src[i + 1];
        int s2 = csr_src[i + 2];
        int s3 = csr_src[i + 3];
        float e0 = es[s0];
        float e1 = es[s1];
        float e2 = es[s2];
        float e3 = es[s3];
        float g0 = h2[(s0 << 5) + c];
        float g1 = h2[(s1 << 5) + c];
        float g2 = h2[(s2 << 5) + c];
        float g3 = h2[(s3 << 5) + c];
        float l0 = e0 + edl; l0 = l0 > 0.f ? l0 : LRELU_SLOPE * l0;
        float l1 = e1 + edl; l1 = l1 > 0.f ? l1 : LRELU_SLOPE * l1;
        float l2 = e2 + edl; l2 = l2 > 0.f ? l2 : LRELU_SLOPE * l2;
        float l3 = e3 + edl; l3 = l3 > 0.f ? l3 : LRELU_SLOPE * l3;
        float w0 = __expf(l0), w1 = __expf(l1), w2 = __expf(l2), w3 = __expf(l3);
        wsum += (w0 + w1) + (w2 + w3);
        acc += w0 * g0 + w1 * g1 + w2 * g2 + w3 * g3;
    }
    for (; i < end; i++) {
        int s = csr_src[i];
        float l = es[s] + edl;
        l = l > 0.f ? l : LRELU_SLOPE * l;
        float w = __expf(l);
        wsum += w;
        acc += w * h2[(s << 5) + c];
    }
    out[(size_t)n * 32 + c] = acc / wsum + b2[c];
}

// ---------------------------------------------------------------------------
extern "C" void kernel_launch(void* const* d_in, const int* in_sizes, int n_in,
                              void* d_out, int out_size, void* d_ws, size_t ws_size,
                              hipStream_t stream) {
    const float* x      = (const float*)d_in[0];
    const int*   ei     = (const int*)  d_in[1];
    const float* W1     = (const float*)d_in[2];
    const float* a_src1 = (const float*)d_in[3];
    const float* a_dst1 = (const float*)d_in[4];
    const float* b1     = (const float*)d_in[5];
    const float* W2     = (const float*)d_in[6];
    const float* a_src2 = (const float*)d_in[7];
    const float* a_dst2 = (const float*)d_in[8];
    const float* b2     = (const float*)d_in[9];
    float* outp = (float*)d_out;

    const int N = in_sizes[0] / 128;   // 50000
    const int E = in_sizes[1] / 2;     // 800000
    const int Etot = E + N;

    const int* src = ei;
    const int* dst = ei + E;

    // workspace layout (bytes); total ~37.8 MB
    char* w = (char*)d_ws;
    unsigned short* h1b = (unsigned short*)(w + 0);          // N*128*2 = 12,800,000
    unsigned short* h1e = (unsigned short*)(w + 12800000);   // N*128*2
    float* h2   = (float*)(w + 25600000);                    // N*32*4 = 6,400,000
    float* es1  = (float*)(w + 32000000);                    // N*4*4
    float* ed1  = (float*)(w + 32800000);                    // N*4*4
    float* es2  = (float*)(w + 33600000);                    // N*4
    float* ed2  = (float*)(w + 33800000);                    // N*4
    int*   deg  = (int*)  (w + 34000000);                    // N*4 (reused as cursor)
    int*   ptr  = (int*)  (w + 34200000);                    // (N+1)*4 (+pad)
    int*   bsum = (int*)  (w + 34400032);                    // 256*4
    int*   csr_src = (int*)(w + 34401056);                   // Etot*4 -> ends 37,801,056

    const int nbA = (N + 1023) / 1024;   // 49

    // --- CSR build (shared by both layers) ---
    zero_int_kernel<<<(N + 255) / 256, 256, 0, stream>>>(deg, N);
    degree_kernel<<<(Etot + 255) / 256, 256, 0, stream>>>(dst, E, N, deg);
    scanA_kernel<<<nbA, 1024, 0, stream>>>(deg, ptr, bsum, N);
    scanB_kernel<<<1, 256, 0, stream>>>(bsum, nbA);
    scanC_kernel<<<(N + 255) / 256, 256, 0, stream>>>(ptr, deg, bsum, N, Etot);
    scatter_kernel<<<(Etot + 255) / 256, 256, 0, stream>>>(src, dst, E, N, deg, csr_src);

    // --- Layer 1 ---
    gemm1_mfma_kernel<<<(N + 63) / 64, 256, 0, stream>>>(x, W1, h1b, N);
    dots1_kernel<<<(N * 4 + 255) / 256, 256, 0, stream>>>(h1b, a_src1, a_dst1, es1, ed1, N * 4);
    agg1_kernel<<<N, 128, 0, stream>>>(h1b, es1, ed1, ptr, csr_src, b1, h1e);

    // --- Layer 2 ---
    gemm2_mfma_kernel<<<(N + 63) / 64, 256, 0, stream>>>(h1e, W2, h2, N);
    dots2_kernel<<<(N + 255) / 256, 256, 0, stream>>>(h2, a_src2, a_dst2, es2, ed2, N);
    agg2_kernel<<<(N + 3) / 4, 128, 0, stream>>>(h2, es2, ed2, ptr, csr_src, b2, outp, N);
}

// Round 5
// 296.125 us; speedup vs baseline: 1.7591x; 1.0307x over previous
//
#include <hip/hip_runtime.h>
#include <hip/hip_bf16.h>

#define LRELU_SLOPE 0.2f

typedef __attribute__((ext_vector_type(8))) short short8;
typedef __attribute__((ext_vector_type(4))) float float4v;

// bf16 <-> fp32 helpers (raw ushort storage)
__device__ inline float b2f(unsigned short u) {
    union { unsigned int i; float f; } v; v.i = ((unsigned int)u) << 16; return v.f;
}
__device__ inline unsigned short f2b(float f) {
    union { float f; unsigned int i; } v; v.f = f;
    unsigned int x = v.i;
    unsigned int r = x + 0x7fffu + ((x >> 16) & 1u);   // round-to-nearest-even
    return (unsigned short)(r >> 16);
}
__device__ inline float lrelu(float x) { return x > 0.f ? x : LRELU_SLOPE * x; }

// ---------------------------------------------------------------------------
// CSR build: degree count -> two-level parallel scan -> scatter (int2 {s,d})
// ---------------------------------------------------------------------------
__global__ void zero_int_kernel(int* __restrict__ p, int n) {
    int i = blockIdx.x * 256 + threadIdx.x;
    if (i < n) p[i] = 0;
}

__global__ void degree_kernel(const int* __restrict__ dst, int E, int N,
                              int* __restrict__ deg) {
    int i = blockIdx.x * 256 + threadIdx.x;
    int total = E + N;
    if (i >= total) return;
    int d = (i < E) ? dst[i] : (i - E);   // self-loops appended
    atomicAdd(&deg[d], 1);
}

__global__ __launch_bounds__(1024) void scanA_kernel(const int* __restrict__ deg,
                                                     int* __restrict__ ptr,
                                                     int* __restrict__ bsum, int N) {
    __shared__ int tile[1024];
    int i = blockIdx.x * 1024 + threadIdx.x;
    int v = (i < N) ? deg[i] : 0;
    tile[threadIdx.x] = v;
    __syncthreads();
    for (int off = 1; off < 1024; off <<= 1) {
        int t = (threadIdx.x >= (unsigned)off) ? tile[threadIdx.x - off] : 0;
        __syncthreads();
        tile[threadIdx.x] += t;
        __syncthreads();
    }
    int incl = tile[threadIdx.x];
    if (i < N) ptr[i] = incl - v;
    if (threadIdx.x == 1023) bsum[blockIdx.x] = incl;
}

__global__ __launch_bounds__(256) void scanB_kernel(int* __restrict__ bsum, int nb) {
    __shared__ int tile[256];
    int v = (threadIdx.x < (unsigned)nb) ? bsum[threadIdx.x] : 0;
    tile[threadIdx.x] = v;
    __syncthreads();
    for (int off = 1; off < 256; off <<= 1) {
        int t = (threadIdx.x >= (unsigned)off) ? tile[threadIdx.x - off] : 0;
        __syncthreads();
        tile[threadIdx.x] += t;
        __syncthreads();
    }
    if (threadIdx.x < (unsigned)nb) bsum[threadIdx.x] = tile[threadIdx.x] - v;
}

__global__ void scanC_kernel(int* __restrict__ ptr, int* __restrict__ cursor,
                             const int* __restrict__ boff, int N, int Etot) {
    int i = blockIdx.x * 256 + threadIdx.x;
    if (i == 0) ptr[N] = Etot;
    if (i >= N) return;
    int p = ptr[i] + boff[i >> 10];
    ptr[i] = p;
    cursor[i] = p;
}

__global__ void scatter_kernel(const int* __restrict__ src,
                               const int* __restrict__ dst, int E, int N,
                               int* __restrict__ cursor,
                               int2* __restrict__ csr) {
    int i = blockIdx.x * 256 + threadIdx.x;
    int total = E + N;
    if (i >= total) return;
    int s, d;
    if (i < E) { s = src[i]; d = dst[i]; }
    else       { s = d = i - E; }
    int pos = atomicAdd(&cursor[d], 1);
    csr[pos] = make_int2(s, d);
}

// ---------------------------------------------------------------------------
// GEMM1 (MFMA bf16): h1b[N][128] = bf16( bf16(x)[N,128] @ bf16(W1)[128,128] )
// ---------------------------------------------------------------------------
__global__ __launch_bounds__(256) void gemm1_mfma_kernel(
        const float* __restrict__ x, const float* __restrict__ W1,
        unsigned short* __restrict__ h1b, int N) {
    __shared__ unsigned short xs[64][136];
    __shared__ unsigned short wt[128][136];
    int tid = threadIdx.x;
    int n0 = blockIdx.x * 64;

    for (int i = tid; i < 128 * 128; i += 256) {
        int k = i >> 7, n = i & 127;
        wt[n][k] = f2b(W1[i]);
    }
    for (int i = tid; i < 64 * 128; i += 256) {
        int r = i >> 7, k = i & 127;
        int row = n0 + r; if (row >= N) row = N - 1;
        xs[r][k] = f2b(x[(size_t)row * 128 + k]);
    }
    __syncthreads();

    int wave = tid >> 6;
    int lane = tid & 63;
    int lrow = lane & 15;
    int quad = lane >> 4;

    short8 afr[4];
#pragma unroll
    for (int kc = 0; kc < 4; kc++)
        afr[kc] = *(const short8*)&xs[wave * 16 + lrow][kc * 32 + quad * 8];

#pragma unroll
    for (int ct = 0; ct < 8; ct++) {
        float4v acc = {0.f, 0.f, 0.f, 0.f};
#pragma unroll
        for (int kc = 0; kc < 4; kc++) {
            short8 bfr = *(const short8*)&wt[ct * 16 + lrow][kc * 32 + quad * 8];
            acc = __builtin_amdgcn_mfma_f32_16x16x32_bf16(afr[kc], bfr, acc, 0, 0, 0);
        }
#pragma unroll
        for (int r = 0; r < 4; r++) {
            int grow = n0 + wave * 16 + quad * 4 + r;
            if (grow < N)
                h1b[grow * 128 + ct * 16 + lrow] = f2b(acc[r]);
        }
    }
}

// ---------------------------------------------------------------------------
// GEMM2 (MFMA bf16): h2b[N][32]bf16 = h1e[N,128]bf16 @ bf16(W2)[128,32]
// ---------------------------------------------------------------------------
__global__ __launch_bounds__(256) void gemm2_mfma_kernel(
        const unsigned short* __restrict__ h1e, const float* __restrict__ W2,
        unsigned short* __restrict__ h2b, int N) {
    __shared__ unsigned short xs[64][136];
    __shared__ unsigned short wt[32][136];
    int tid = threadIdx.x;
    int n0 = blockIdx.x * 64;

    for (int i = tid; i < 128 * 32; i += 256) {
        int k = i >> 5, n = i & 31;
        wt[n][k] = f2b(W2[i]);
    }
    {
        const unsigned int* srcp = (const unsigned int*)(h1e + (size_t)n0 * 128);
        int rows = (N - n0) < 64 ? (N - n0) : 64;
        int maxu = rows * 64;
        for (int i = tid; i < 4096; i += 256) {
            unsigned int v = (i < maxu) ? srcp[i] : 0u;
            int r = i >> 6, cp = (i & 63) << 1;
            *(unsigned int*)&xs[r][cp] = v;
        }
    }
    __syncthreads();

    int wave = tid >> 6;
    int lane = tid & 63;
    int lrow = lane & 15;
    int quad = lane >> 4;

    short8 afr[4];
#pragma unroll
    for (int kc = 0; kc < 4; kc++)
        afr[kc] = *(const short8*)&xs[wave * 16 + lrow][kc * 32 + quad * 8];

#pragma unroll
    for (int ct = 0; ct < 2; ct++) {
        float4v acc = {0.f, 0.f, 0.f, 0.f};
#pragma unroll
        for (int kc = 0; kc < 4; kc++) {
            short8 bfr = *(const short8*)&wt[ct * 16 + lrow][kc * 32 + quad * 8];
            acc = __builtin_amdgcn_mfma_f32_16x16x32_bf16(afr[kc], bfr, acc, 0, 0, 0);
        }
#pragma unroll
        for (int r = 0; r < 4; r++) {
            int grow = n0 + wave * 16 + quad * 4 + r;
            if (grow < N)
                h2b[(size_t)grow * 32 + ct * 16 + lrow] = f2b(acc[r]);
        }
    }
}

// ---------------------------------------------------------------------------
// Attention logit dots
// ---------------------------------------------------------------------------
__global__ void dots1_kernel(const unsigned short* __restrict__ h1b,
                             const float* __restrict__ a_src,
                             const float* __restrict__ a_dst,
                             float* __restrict__ es, float* __restrict__ ed,
                             int N4) {
    int t = blockIdx.x * 256 + threadIdx.x;
    if (t >= N4) return;
    int h = t & 3;
    const unsigned int* hp = (const unsigned int*)(h1b + (size_t)t * 32);
    const float* ap = a_src + h * 32;
    const float* bp = a_dst + h * 32;
    float s = 0.f, d = 0.f;
#pragma unroll
    for (int j = 0; j < 16; j++) {
        unsigned int u = hp[j];
        float v0 = b2f((unsigned short)(u & 0xffffu));
        float v1 = b2f((unsigned short)(u >> 16));
        s += v0 * ap[2 * j] + v1 * ap[2 * j + 1];
        d += v0 * bp[2 * j] + v1 * bp[2 * j + 1];
    }
    es[t] = s; ed[t] = d;
}

__global__ void dots2_kernel(const unsigned short* __restrict__ h2b,
                             const float* __restrict__ a_src,
                             const float* __restrict__ a_dst,
                             float* __restrict__ es, float* __restrict__ ed,
                             int N) {
    int t = blockIdx.x * 256 + threadIdx.x;
    if (t >= N) return;
    const unsigned int* hp = (const unsigned int*)(h2b + (size_t)t * 32);
    const float* ap = a_src;
    const float* bp = a_dst;
    float s = 0.f, d = 0.f;
#pragma unroll
    for (int j = 0; j < 16; j++) {
        unsigned int u = hp[j];
        float v0 = b2f((unsigned short)(u & 0xffffu));
        float v1 = b2f((unsigned short)(u >> 16));
        s += v0 * ap[2 * j] + v1 * ap[2 * j + 1];
        d += v0 * bp[2 * j] + v1 * bp[2 * j + 1];
    }
    es[t] = s; ed[t] = d;
}

// ---------------------------------------------------------------------------
// Edge-weight precompute (removes exp/lrelu/es/ed from the replicated agg loops)
// ---------------------------------------------------------------------------
__global__ void weights1_kernel(const int2* __restrict__ csr,
                                const float* __restrict__ es,
                                const float* __restrict__ ed,
                                float* __restrict__ w1, int Etot) {
    int e = blockIdx.x * 256 + threadIdx.x;
    if (e >= Etot) return;
    int2 sd = csr[e];
    float4 a = *(const float4*)&es[sd.x * 4];
    float4 b = *(const float4*)&ed[sd.y * 4];
    float4 w;
    w.x = __expf(lrelu(a.x + b.x));
    w.y = __expf(lrelu(a.y + b.y));
    w.z = __expf(lrelu(a.z + b.z));
    w.w = __expf(lrelu(a.w + b.w));
    *(float4*)&w1[(size_t)e * 4] = w;
}

__global__ void weights2_kernel(const int2* __restrict__ csr,
                                const float* __restrict__ es,
                                const float* __restrict__ ed,
                                float* __restrict__ w2, int Etot) {
    int e = blockIdx.x * 256 + threadIdx.x;
    if (e >= Etot) return;
    int2 sd = csr[e];
    w2[e] = __expf(lrelu(es[sd.x] + ed[sd.y]));
}

// ---------------------------------------------------------------------------
// Aggregation layer 1: one node per WAVE (64 lanes x 2 packed-bf16 channels).
// Block 256 = 4 nodes. Inner loop: broadcast csr.x + broadcast w + uint gather.
// Epilogue: /wsum, +b1, ELU, pack bf16 -> h1e.
// ---------------------------------------------------------------------------
__global__ __launch_bounds__(256) void agg1_kernel(
        const unsigned int* __restrict__ h1u, const float* __restrict__ w1,
        const int2* __restrict__ csr, const int* __restrict__ ptr,
        const float* __restrict__ b1, unsigned int* __restrict__ h1e_u, int N) {
    int wave = threadIdx.x >> 6;
    int lane = threadIdx.x & 63;
    int n = blockIdx.x * 4 + wave;
    if (n >= N) return;
    int h = lane >> 4;                 // head of channels 2*lane, 2*lane+1
    int start = ptr[n], end = ptr[n + 1];
    float acc0 = 0.f, acc1 = 0.f, wsum = 0.f;
    int i = start;
    for (; i + 4 <= end; i += 4) {
        int s0 = csr[i + 0].x;
        int s1 = csr[i + 1].x;
        int s2 = csr[i + 2].x;
        int s3 = csr[i + 3].x;
        float v0 = w1[(size_t)(i + 0) * 4 + h];
        float v1 = w1[(size_t)(i + 1) * 4 + h];
        float v2 = w1[(size_t)(i + 2) * 4 + h];
        float v3 = w1[(size_t)(i + 3) * 4 + h];
        unsigned int g0 = h1u[(s0 << 6) + lane];
        unsigned int g1 = h1u[(s1 << 6) + lane];
        unsigned int g2 = h1u[(s2 << 6) + lane];
        unsigned int g3 = h1u[(s3 << 6) + lane];
        acc0 += v0 * b2f((unsigned short)(g0 & 0xffffu))
              + v1 * b2f((unsigned short)(g1 & 0xffffu))
              + v2 * b2f((unsigned short)(g2 & 0xffffu))
              + v3 * b2f((unsigned short)(g3 & 0xffffu));
        acc1 += v0 * b2f((unsigned short)(g0 >> 16))
              + v1 * b2f((unsigned short)(g1 >> 16))
              + v2 * b2f((unsigned short)(g2 >> 16))
              + v3 * b2f((unsigned short)(g3 >> 16));
        wsum += (v0 + v1) + (v2 + v3);
    }
    for (; i < end; i++) {
        int s = csr[i].x;
        float v = w1[(size_t)i * 4 + h];
        unsigned int g = h1u[(s << 6) + lane];
        acc0 += v * b2f((unsigned short)(g & 0xffffu));
        acc1 += v * b2f((unsigned short)(g >> 16));
        wsum += v;
    }
    float r = 1.f / wsum;
    float2 bb = ((const float2*)b1)[lane];
    float o0 = acc0 * r + bb.x;
    float o1 = acc1 * r + bb.y;
    o0 = o0 > 0.f ? o0 : __expf(o0) - 1.f;
    o1 = o1 > 0.f ? o1 : __expf(o1) - 1.f;
    h1e_u[(n << 6) + lane] = (unsigned int)f2b(o0) | ((unsigned int)f2b(o1) << 16);
}

// ---------------------------------------------------------------------------
// Aggregation layer 2: 16 lanes/node x 2 packed-bf16 channels; 4 nodes/wave,
// 16 nodes per 256-thread block. fp32 accumulate, fp32 output.
// ---------------------------------------------------------------------------
__global__ __launch_bounds__(256) void agg2_kernel(
        const unsigned int* __restrict__ h2u, const float* __restrict__ w2,
        const int2* __restrict__ csr, const int* __restrict__ ptr,
        const float* __restrict__ b2, float* __restrict__ out, int N) {
    int lane = threadIdx.x & 63;
    int g = lane >> 4;
    int n = blockIdx.x * 16 + (threadIdx.x >> 6) * 4 + g;
    if (n >= N) return;
    int cl = lane & 15;                // channel-pair index (channels 2cl, 2cl+1)
    int start = ptr[n], end = ptr[n + 1];
    float acc0 = 0.f, acc1 = 0.f, wsum = 0.f;
    int i = start;
    for (; i + 4 <= end; i += 4) {
        int s0 = csr[i + 0].x;
        int s1 = csr[i + 1].x;
        int s2 = csr[i + 2].x;
        int s3 = csr[i + 3].x;
        float v0 = w2[i + 0];
        float v1 = w2[i + 1];
        float v2 = w2[i + 2];
        float v3 = w2[i + 3];
        unsigned int g0 = h2u[(s0 << 4) + cl];
        unsigned int g1 = h2u[(s1 << 4) + cl];
        unsigned int g2 = h2u[(s2 << 4) + cl];
        unsigned int g3 = h2u[(s3 << 4) + cl];
        acc0 += v0 * b2f((unsigned short)(g0 & 0xffffu))
              + v1 * b2f((unsigned short)(g1 & 0xffffu))
              + v2 * b2f((unsigned short)(g2 & 0xffffu))
              + v3 * b2f((unsigned short)(g3 & 0xffffu));
        acc1 += v0 * b2f((unsigned short)(g0 >> 16))
              + v1 * b2f((unsigned short)(g1 >> 16))
              + v2 * b2f((unsigned short)(g2 >> 16))
              + v3 * b2f((unsigned short)(g3 >> 16));
        wsum += (v0 + v1) + (v2 + v3);
    }
    for (; i < end; i++) {
        int s = csr[i].x;
        float v = w2[i];
        unsigned int gg = h2u[(s << 4) + cl];
        acc0 += v * b2f((unsigned short)(gg & 0xffffu));
        acc1 += v * b2f((unsigned short)(gg >> 16));
        wsum += v;
    }
    float r = 1.f / wsum;
    float2 bb = ((const float2*)b2)[cl];
    float2 o;
    o.x = acc0 * r + bb.x;
    o.y = acc1 * r + bb.y;
    ((float2*)out)[(size_t)n * 16 + cl] = o;
}

// ---------------------------------------------------------------------------
extern "C" void kernel_launch(void* const* d_in, const int* in_sizes, int n_in,
                              void* d_out, int out_size, void* d_ws, size_t ws_size,
                              hipStream_t stream) {
    const float* x      = (const float*)d_in[0];
    const int*   ei     = (const int*)  d_in[1];
    const float* W1     = (const float*)d_in[2];
    const float* a_src1 = (const float*)d_in[3];
    const float* a_dst1 = (const float*)d_in[4];
    const float* b1     = (const float*)d_in[5];
    const float* W2     = (const float*)d_in[6];
    const float* a_src2 = (const float*)d_in[7];
    const float* a_dst2 = (const float*)d_in[8];
    const float* b2     = (const float*)d_in[9];
    float* outp = (float*)d_out;

    const int N = in_sizes[0] / 128;   // 50000
    const int E = in_sizes[1] / 2;     // 800000
    const int Etot = E + N;            // 850000

    const int* src = ei;
    const int* dst = ei + E;

    // workspace layout (bytes); total ~55.0 MB
    char* w = (char*)d_ws;
    unsigned short* h1b = (unsigned short*)(w + 0);          // 12,800,000
    unsigned short* h1e = (unsigned short*)(w + 12800000);   // 12,800,000
    unsigned short* h2b = (unsigned short*)(w + 25600000);   //  3,200,000
    float* es1  = (float*)(w + 28800000);                    //    800,000
    float* ed1  = (float*)(w + 29600000);                    //    800,000
    float* es2  = (float*)(w + 30400000);                    //    200,000
    float* ed2  = (float*)(w + 30600000);                    //    200,000
    int*   deg  = (int*)  (w + 30800000);                    //    200,000 (cursor)
    int*   ptr  = (int*)  (w + 31000000);                    //    200,064
    int*   bsum = (int*)  (w + 31200064);                    //      1,024
    int2*  csr  = (int2*) (w + 31201088);                    //  6,800,000
    float* w1   = (float*)(w + 38001088);                    // 13,600,000
    float* w2   = (float*)(w + 51601088);                    //  3,400,000 -> 55,001,088

    const int nbA = (N + 1023) / 1024;   // 49

    // --- CSR build (shared by both layers) ---
    zero_int_kernel<<<(N + 255) / 256, 256, 0, stream>>>(deg, N);
    degree_kernel<<<(Etot + 255) / 256, 256, 0, stream>>>(dst, E, N, deg);
    scanA_kernel<<<nbA, 1024, 0, stream>>>(deg, ptr, bsum, N);
    scanB_kernel<<<1, 256, 0, stream>>>(bsum, nbA);
    scanC_kernel<<<(N + 255) / 256, 256, 0, stream>>>(ptr, deg, bsum, N, Etot);
    scatter_kernel<<<(Etot + 255) / 256, 256, 0, stream>>>(src, dst, E, N, deg, csr);

    // --- Layer 1 ---
    gemm1_mfma_kernel<<<(N + 63) / 64, 256, 0, stream>>>(x, W1, h1b, N);
    dots1_kernel<<<(N * 4 + 255) / 256, 256, 0, stream>>>(h1b, a_src1, a_dst1, es1, ed1, N * 4);
    weights1_kernel<<<(Etot + 255) / 256, 256, 0, stream>>>(csr, es1, ed1, w1, Etot);
    agg1_kernel<<<(N + 3) / 4, 256, 0, stream>>>((const unsigned int*)h1b, w1, csr, ptr,
                                                 b1, (unsigned int*)h1e, N);

    // --- Layer 2 ---
    gemm2_mfma_kernel<<<(N + 63) / 64, 256, 0, stream>>>(h1e, W2, h2b, N);
    dots2_kernel<<<(N + 255) / 256, 256, 0, stream>>>(h2b, a_src2, a_dst2, es2, ed2, N);
    weights2_kernel<<<(Etot + 255) / 256, 256, 0, stream>>>(csr, es2, ed2, w2, Etot);
    agg2_kernel<<<(N + 15) / 16, 256, 0, stream>>>((const unsigned int*)h2b, w2, csr, ptr,
                                                   b2, outp, N);
}

// Round 6
// 229.839 us; speedup vs baseline: 2.2665x; 1.2884x over previous
//
#include <hip/hip_runtime.h>
#include <hip/hip_bf16.h>

#define LRELU_SLOPE 0.2f
#define NB_SHIFT 7          // 128 dst-nodes per bucket

typedef __attribute__((ext_vector_type(8))) short short8;
typedef __attribute__((ext_vector_type(4))) float float4v;

// bf16 <-> fp32 helpers (raw ushort storage)
__device__ inline float b2f(unsigned short u) {
    union { unsigned int i; float f; } v; v.i = ((unsigned int)u) << 16; return v.f;
}
__device__ inline unsigned short f2b(float f) {
    union { float f; unsigned int i; } v; v.f = f;
    unsigned int x = v.i;
    unsigned int r = x + 0x7fffu + ((x >> 16) & 1u);   // round-to-nearest-even
    return (unsigned short)(r >> 16);
}
__device__ inline float lrelu(float x) { return x > 0.f ? x : LRELU_SLOPE * x; }

// ---------------------------------------------------------------------------
// CSR build, pass 1: per-block bucket histogram.  cnt[bucket*nblk + block]
// ---------------------------------------------------------------------------
__global__ __launch_bounds__(256) void hist_kernel(const int* __restrict__ dst,
                                                   int E, int Etot, int nb, int nblk,
                                                   int chunk, int* __restrict__ cnt) {
    __shared__ int hist[512];
    int blk = blockIdx.x;
    for (int i = threadIdx.x; i < nb; i += 256) hist[i] = 0;
    __syncthreads();
    int lo = blk * chunk;
    int hi = lo + chunk; if (hi > Etot) hi = Etot;
    for (int i = lo + threadIdx.x; i < hi; i += 256) {
        int d = (i < E) ? dst[i] : (i - E);
        atomicAdd(&hist[d >> NB_SHIFT], 1);
    }
    __syncthreads();
    for (int b = threadIdx.x; b < nb; b += 256)
        cnt[b * nblk + blk] = hist[b];
}

// in-place block-local exclusive scan (1024/block) + block totals
__global__ __launch_bounds__(1024) void scanA_kernel(int* cnt, int* bsum, int M) {
    __shared__ int tile[1024];
    int i = blockIdx.x * 1024 + threadIdx.x;
    int v = (i < M) ? cnt[i] : 0;
    tile[threadIdx.x] = v;
    __syncthreads();
    for (int off = 1; off < 1024; off <<= 1) {
        int t = (threadIdx.x >= (unsigned)off) ? tile[threadIdx.x - off] : 0;
        __syncthreads();
        tile[threadIdx.x] += t;
        __syncthreads();
    }
    int incl = tile[threadIdx.x];
    if (i < M) cnt[i] = incl - v;
    if (threadIdx.x == 1023) bsum[blockIdx.x] = incl;
}

__global__ __launch_bounds__(256) void scanB_kernel(int* __restrict__ bsum, int nb) {
    __shared__ int tile[256];
    int v = (threadIdx.x < (unsigned)nb) ? bsum[threadIdx.x] : 0;
    tile[threadIdx.x] = v;
    __syncthreads();
    for (int off = 1; off < 256; off <<= 1) {
        int t = (threadIdx.x >= (unsigned)off) ? tile[threadIdx.x - off] : 0;
        __syncthreads();
        tile[threadIdx.x] += t;
        __syncthreads();
    }
    if (threadIdx.x < (unsigned)nb) bsum[threadIdx.x] = tile[threadIdx.x] - v;
}

// ---------------------------------------------------------------------------
// CSR build, pass 2: partition edges into bucket array. LDS cursors hold
// global offsets (scan value), so each block writes a dense exclusive
// sub-region per bucket. No global atomics.
// ---------------------------------------------------------------------------
__global__ __launch_bounds__(256) void partition_kernel(
        const int* __restrict__ src, const int* __restrict__ dst,
        int E, int Etot, int nb, int nblk, int chunk,
        const int* __restrict__ cnt, const int* __restrict__ boff,
        int2* __restrict__ bkt) {
    __shared__ int cur[512];
    int blk = blockIdx.x;
    for (int b = threadIdx.x; b < nb; b += 256) {
        int idx = b * nblk + blk;
        cur[b] = cnt[idx] + boff[idx >> 10];
    }
    __syncthreads();
    int lo = blk * chunk;
    int hi = lo + chunk; if (hi > Etot) hi = Etot;
    for (int i = lo + threadIdx.x; i < hi; i += 256) {
        int s, d;
        if (i < E) { s = src[i]; d = dst[i]; }
        else       { s = d = i - E; }
        int pos = atomicAdd(&cur[d >> NB_SHIFT], 1);
        bkt[pos] = make_int2(s, d);
    }
}

// ---------------------------------------------------------------------------
// CSR build, pass 3 (one block per bucket): local degree count -> LDS scan ->
// write ptr; place edges at final CSR positions (dense 17 KB region);
// fold in layer-1 edge-weight computation (w1[e][h] = exp(lrelu(es+ed))).
// ---------------------------------------------------------------------------
__global__ __launch_bounds__(256) void finalize_kernel(
        const int2* __restrict__ bkt, const int* __restrict__ cnt,
        const int* __restrict__ boff, int nb, int nblk,
        const float* __restrict__ es, const float* __restrict__ ed,
        int* __restrict__ ptr, int2* __restrict__ csr, float* __restrict__ w1,
        int N, int Etot) {
    __shared__ int deg[128];
    __shared__ int scn[128];
    __shared__ int cur[128];
    int b = blockIdx.x;
    int idx0 = b * nblk;
    int base = cnt[idx0] + boff[idx0 >> 10];
    int nextbase;
    if (b + 1 < nb) {
        int idx1 = (b + 1) * nblk;
        nextbase = cnt[idx1] + boff[idx1 >> 10];
    } else nextbase = Etot;
    int count = nextbase - base;
    int node0 = b << NB_SHIFT;
    int nodes = N - node0; if (nodes > 128) nodes = 128;

    if (threadIdx.x < 128) deg[threadIdx.x] = 0;
    __syncthreads();
    for (int i = threadIdx.x; i < count; i += 256)
        atomicAdd(&deg[bkt[base + i].y - node0], 1);
    __syncthreads();
    int v = (threadIdx.x < 128) ? deg[threadIdx.x] : 0;
    if (threadIdx.x < 128) scn[threadIdx.x] = v;
    __syncthreads();
    for (int off = 1; off < 128; off <<= 1) {
        int t = (threadIdx.x < 128 && threadIdx.x >= (unsigned)off) ? scn[threadIdx.x - off] : 0;
        __syncthreads();
        if (threadIdx.x < 128) scn[threadIdx.x] += t;
        __syncthreads();
    }
    if (threadIdx.x < 128) {
        int excl = scn[threadIdx.x] - v;
        cur[threadIdx.x] = excl;
        if (threadIdx.x < nodes) ptr[node0 + threadIdx.x] = base + excl;
    }
    if (b == nb - 1 && threadIdx.x == 0) ptr[N] = Etot;
    __syncthreads();
    for (int i = threadIdx.x; i < count; i += 256) {
        int2 sd = bkt[base + i];
        int pos = base + atomicAdd(&cur[sd.y - node0], 1);
        csr[pos] = sd;
        float4 a = *(const float4*)&es[sd.x * 4];
        float4 bb = *(const float4*)&ed[sd.y * 4];
        float4 ww;
        ww.x = __expf(lrelu(a.x + bb.x));
        ww.y = __expf(lrelu(a.y + bb.y));
        ww.z = __expf(lrelu(a.z + bb.z));
        ww.w = __expf(lrelu(a.w + bb.w));
        *(float4*)&w1[(size_t)pos * 4] = ww;
    }
}

// ---------------------------------------------------------------------------
// GEMM1 (MFMA bf16): h1b[N][128] = bf16( bf16(x)[N,128] @ bf16(W1)[128,128] )
// ---------------------------------------------------------------------------
__global__ __launch_bounds__(256) void gemm1_mfma_kernel(
        const float* __restrict__ x, const float* __restrict__ W1,
        unsigned short* __restrict__ h1b, int N) {
    __shared__ unsigned short xs[64][136];
    __shared__ unsigned short wt[128][136];
    int tid = threadIdx.x;
    int n0 = blockIdx.x * 64;

    for (int i = tid; i < 128 * 128; i += 256) {
        int k = i >> 7, n = i & 127;
        wt[n][k] = f2b(W1[i]);
    }
    for (int i = tid; i < 64 * 128; i += 256) {
        int r = i >> 7, k = i & 127;
        int row = n0 + r; if (row >= N) row = N - 1;
        xs[r][k] = f2b(x[(size_t)row * 128 + k]);
    }
    __syncthreads();

    int wave = tid >> 6;
    int lane = tid & 63;
    int lrow = lane & 15;
    int quad = lane >> 4;

    short8 afr[4];
#pragma unroll
    for (int kc = 0; kc < 4; kc++)
        afr[kc] = *(const short8*)&xs[wave * 16 + lrow][kc * 32 + quad * 8];

#pragma unroll
    for (int ct = 0; ct < 8; ct++) {
        float4v acc = {0.f, 0.f, 0.f, 0.f};
#pragma unroll
        for (int kc = 0; kc < 4; kc++) {
            short8 bfr = *(const short8*)&wt[ct * 16 + lrow][kc * 32 + quad * 8];
            acc = __builtin_amdgcn_mfma_f32_16x16x32_bf16(afr[kc], bfr, acc, 0, 0, 0);
        }
#pragma unroll
        for (int r = 0; r < 4; r++) {
            int grow = n0 + wave * 16 + quad * 4 + r;
            if (grow < N)
                h1b[grow * 128 + ct * 16 + lrow] = f2b(acc[r]);
        }
    }
}

// ---------------------------------------------------------------------------
// GEMM2 (MFMA bf16): h2b[N][32]bf16 = h1e[N,128]bf16 @ bf16(W2)[128,32]
// ---------------------------------------------------------------------------
__global__ __launch_bounds__(256) void gemm2_mfma_kernel(
        const unsigned short* __restrict__ h1e, const float* __restrict__ W2,
        unsigned short* __restrict__ h2b, int N) {
    __shared__ unsigned short xs[64][136];
    __shared__ unsigned short wt[32][136];
    int tid = threadIdx.x;
    int n0 = blockIdx.x * 64;

    for (int i = tid; i < 128 * 32; i += 256) {
        int k = i >> 5, n = i & 31;
        wt[n][k] = f2b(W2[i]);
    }
    {
        const unsigned int* srcp = (const unsigned int*)(h1e + (size_t)n0 * 128);
        int rows = (N - n0) < 64 ? (N - n0) : 64;
        int maxu = rows * 64;
        for (int i = tid; i < 4096; i += 256) {
            unsigned int v = (i < maxu) ? srcp[i] : 0u;
            int r = i >> 6, cp = (i & 63) << 1;
            *(unsigned int*)&xs[r][cp] = v;
        }
    }
    __syncthreads();

    int wave = tid >> 6;
    int lane = tid & 63;
    int lrow = lane & 15;
    int quad = lane >> 4;

    short8 afr[4];
#pragma unroll
    for (int kc = 0; kc < 4; kc++)
        afr[kc] = *(const short8*)&xs[wave * 16 + lrow][kc * 32 + quad * 8];

#pragma unroll
    for (int ct = 0; ct < 2; ct++) {
        float4v acc = {0.f, 0.f, 0.f, 0.f};
#pragma unroll
        for (int kc = 0; kc < 4; kc++) {
            short8 bfr = *(const short8*)&wt[ct * 16 + lrow][kc * 32 + quad * 8];
            acc = __builtin_amdgcn_mfma_f32_16x16x32_bf16(afr[kc], bfr, acc, 0, 0, 0);
        }
#pragma unroll
        for (int r = 0; r < 4; r++) {
            int grow = n0 + wave * 16 + quad * 4 + r;
            if (grow < N)
                h2b[(size_t)grow * 32 + ct * 16 + lrow] = f2b(acc[r]);
        }
    }
}

// ---------------------------------------------------------------------------
// Attention logit dots
// ---------------------------------------------------------------------------
__global__ void dots1_kernel(const unsigned short* __restrict__ h1b,
                             const float* __restrict__ a_src,
                             const float* __restrict__ a_dst,
                             float* __restrict__ es, float* __restrict__ ed,
                             int N4) {
    int t = blockIdx.x * 256 + threadIdx.x;
    if (t >= N4) return;
    int h = t & 3;
    const unsigned int* hp = (const unsigned int*)(h1b + (size_t)t * 32);
    const float* ap = a_src + h * 32;
    const float* bp = a_dst + h * 32;
    float s = 0.f, d = 0.f;
#pragma unroll
    for (int j = 0; j < 16; j++) {
        unsigned int u = hp[j];
        float v0 = b2f((unsigned short)(u & 0xffffu));
        float v1 = b2f((unsigned short)(u >> 16));
        s += v0 * ap[2 * j] + v1 * ap[2 * j + 1];
        d += v0 * bp[2 * j] + v1 * bp[2 * j + 1];
    }
    es[t] = s; ed[t] = d;
}

__global__ void dots2_kernel(const unsigned short* __restrict__ h2b,
                             const float* __restrict__ a_src,
                             const float* __restrict__ a_dst,
                             float* __restrict__ es, float* __restrict__ ed,
                             int N) {
    int t = blockIdx.x * 256 + threadIdx.x;
    if (t >= N) return;
    const unsigned int* hp = (const unsigned int*)(h2b + (size_t)t * 32);
    const float* ap = a_src;
    const float* bp = a_dst;
    float s = 0.f, d = 0.f;
#pragma unroll
    for (int j = 0; j < 16; j++) {
        unsigned int u = hp[j];
        float v0 = b2f((unsigned short)(u & 0xffffu));
        float v1 = b2f((unsigned short)(u >> 16));
        s += v0 * ap[2 * j] + v1 * ap[2 * j + 1];
        d += v0 * bp[2 * j] + v1 * bp[2 * j + 1];
    }
    es[t] = s; ed[t] = d;
}

__global__ void weights2_kernel(const int2* __restrict__ csr,
                                const float* __restrict__ es,
                                const float* __restrict__ ed,
                                float* __restrict__ w2, int Etot) {
    int e = blockIdx.x * 256 + threadIdx.x;
    if (e >= Etot) return;
    int2 sd = csr[e];
    w2[e] = __expf(lrelu(es[sd.x] + ed[sd.y]));
}

// ---------------------------------------------------------------------------
// Aggregation layer 1: one node per WAVE (64 lanes x 2 packed-bf16 channels).
// ---------------------------------------------------------------------------
__global__ __launch_bounds__(256) void agg1_kernel(
        const unsigned int* __restrict__ h1u, const float* __restrict__ w1,
        const int2* __restrict__ csr, const int* __restrict__ ptr,
        const float* __restrict__ b1, unsigned int* __restrict__ h1e_u, int N) {
    int wave = threadIdx.x >> 6;
    int lane = threadIdx.x & 63;
    int n = blockIdx.x * 4 + wave;
    if (n >= N) return;
    int h = lane >> 4;
    int start = ptr[n], end = ptr[n + 1];
    float acc0 = 0.f, acc1 = 0.f, wsum = 0.f;
    int i = start;
    for (; i + 4 <= end; i += 4) {
        int s0 = csr[i + 0].x;
        int s1 = csr[i + 1].x;
        int s2 = csr[i + 2].x;
        int s3 = csr[i + 3].x;
        float v0 = w1[(size_t)(i + 0) * 4 + h];
        float v1 = w1[(size_t)(i + 1) * 4 + h];
        float v2 = w1[(size_t)(i + 2) * 4 + h];
        float v3 = w1[(size_t)(i + 3) * 4 + h];
        unsigned int g0 = h1u[(s0 << 6) + lane];
        unsigned int g1 = h1u[(s1 << 6) + lane];
        unsigned int g2 = h1u[(s2 << 6) + lane];
        unsigned int g3 = h1u[(s3 << 6) + lane];
        acc0 += v0 * b2f((unsigned short)(g0 & 0xffffu))
              + v1 * b2f((unsigned short)(g1 & 0xffffu))
              + v2 * b2f((unsigned short)(g2 & 0xffffu))
              + v3 * b2f((unsigned short)(g3 & 0xffffu));
        acc1 += v0 * b2f((unsigned short)(g0 >> 16))
              + v1 * b2f((unsigned short)(g1 >> 16))
              + v2 * b2f((unsigned short)(g2 >> 16))
              + v3 * b2f((unsigned short)(g3 >> 16));
        wsum += (v0 + v1) + (v2 + v3);
    }
    for (; i < end; i++) {
        int s = csr[i].x;
        float v = w1[(size_t)i * 4 + h];
        unsigned int g = h1u[(s << 6) + lane];
        acc0 += v * b2f((unsigned short)(g & 0xffffu));
        acc1 += v * b2f((unsigned short)(g >> 16));
        wsum += v;
    }
    float r = 1.f / wsum;
    float2 bb = ((const float2*)b1)[lane];
    float o0 = acc0 * r + bb.x;
    float o1 = acc1 * r + bb.y;
    o0 = o0 > 0.f ? o0 : __expf(o0) - 1.f;
    o1 = o1 > 0.f ? o1 : __expf(o1) - 1.f;
    h1e_u[(n << 6) + lane] = (unsigned int)f2b(o0) | ((unsigned int)f2b(o1) << 16);
}

// ---------------------------------------------------------------------------
// Aggregation layer 2: 16 lanes/node x 2 packed-bf16 channels.
// ---------------------------------------------------------------------------
__global__ __launch_bounds__(256) void agg2_kernel(
        const unsigned int* __restrict__ h2u, const float* __restrict__ w2,
        const int2* __restrict__ csr, const int* __restrict__ ptr,
        const float* __restrict__ b2, float* __restrict__ out, int N) {
    int lane = threadIdx.x & 63;
    int g = lane >> 4;
    int n = blockIdx.x * 16 + (threadIdx.x >> 6) * 4 + g;
    if (n >= N) return;
    int cl = lane & 15;
    int start = ptr[n], end = ptr[n + 1];
    float acc0 = 0.f, acc1 = 0.f, wsum = 0.f;
    int i = start;
    for (; i + 4 <= end; i += 4) {
        int s0 = csr[i + 0].x;
        int s1 = csr[i + 1].x;
        int s2 = csr[i + 2].x;
        int s3 = csr[i + 3].x;
        float v0 = w2[i + 0];
        float v1 = w2[i + 1];
        float v2 = w2[i + 2];
        float v3 = w2[i + 3];
        unsigned int g0 = h2u[(s0 << 4) + cl];
        unsigned int g1 = h2u[(s1 << 4) + cl];
        unsigned int g2 = h2u[(s2 << 4) + cl];
        unsigned int g3 = h2u[(s3 << 4) + cl];
        acc0 += v0 * b2f((unsigned short)(g0 & 0xffffu))
              + v1 * b2f((unsigned short)(g1 & 0xffffu))
              + v2 * b2f((unsigned short)(g2 & 0xffffu))
              + v3 * b2f((unsigned short)(g3 & 0xffffu));
        acc1 += v0 * b2f((unsigned short)(g0 >> 16))
              + v1 * b2f((unsigned short)(g1 >> 16))
              + v2 * b2f((unsigned short)(g2 >> 16))
              + v3 * b2f((unsigned short)(g3 >> 16));
        wsum += (v0 + v1) + (v2 + v3);
    }
    for (; i < end; i++) {
        int s = csr[i].x;
        float v = w2[i];
        unsigned int gg = h2u[(s << 4) + cl];
        acc0 += v * b2f((unsigned short)(gg & 0xffffu));
        acc1 += v * b2f((unsigned short)(gg >> 16));
        wsum += v;
    }
    float r = 1.f / wsum;
    float2 bb = ((const float2*)b2)[cl];
    float2 o;
    o.x = acc0 * r + bb.x;
    o.y = acc1 * r + bb.y;
    ((float2*)out)[(size_t)n * 16 + cl] = o;
}

// ---------------------------------------------------------------------------
extern "C" void kernel_launch(void* const* d_in, const int* in_sizes, int n_in,
                              void* d_out, int out_size, void* d_ws, size_t ws_size,
                              hipStream_t stream) {
    const float* x      = (const float*)d_in[0];
    const int*   ei     = (const int*)  d_in[1];
    const float* W1     = (const float*)d_in[2];
    const float* a_src1 = (const float*)d_in[3];
    const float* a_dst1 = (const float*)d_in[4];
    const float* b1     = (const float*)d_in[5];
    const float* W2     = (const float*)d_in[6];
    const float* a_src2 = (const float*)d_in[7];
    const float* a_dst2 = (const float*)d_in[8];
    const float* b2     = (const float*)d_in[9];
    float* outp = (float*)d_out;

    const int N = in_sizes[0] / 128;   // 50000
    const int E = in_sizes[1] / 2;     // 800000
    const int Etot = E + N;            // 850000

    const int* src = ei;
    const int* dst = ei + E;

    const int nb   = (N + 127) >> 7;                 // 391 buckets
    const int nblk = 128;                            // hist/partition blocks
    const int chunk = (Etot + nblk - 1) / nblk;      // 6641
    const int M = nb * nblk;                         // 50048 scan elements
    const int nbA = (M + 1023) / 1024;               // 49

    // workspace layout (bytes); total ~61.8 MB (< R1's proven 63.4 MB)
    char* w = (char*)d_ws;
    unsigned short* h1b = (unsigned short*)(w + 0);          // 12,800,000
    unsigned short* h1e = (unsigned short*)(w + 12800000);   // 12,800,000
    unsigned short* h2b = (unsigned short*)(w + 25600000);   //  3,200,000
    float* es1  = (float*)(w + 28800000);                    //    800,000
    float* ed1  = (float*)(w + 29600000);                    //    800,000
    float* es2  = (float*)(w + 30400000);                    //    200,000
    float* ed2  = (float*)(w + 30600000);                    //    200,000
    int*   ptr  = (int*)  (w + 30800000);                    //    200,064
    int*   bsum = (int*)  (w + 31000064);                    //      1,024
    int*   cnt  = (int*)  (w + 31001088);                    //    200,192
    int2*  csr  = (int2*) (w + 31201280);                    //  6,800,000
    int2*  bkt  = (int2*) (w + 38001280);                    //  6,800,000
    float* w1   = (float*)(w + 44801280);                    // 13,600,000
    float* w2   = (float*)(w + 58401280);                    //  3,400,000 -> 61,801,280

    // --- Layer-1 GEMM + logits (CSR-independent, needed by finalize) ---
    gemm1_mfma_kernel<<<(N + 63) / 64, 256, 0, stream>>>(x, W1, h1b, N);
    dots1_kernel<<<(N * 4 + 255) / 256, 256, 0, stream>>>(h1b, a_src1, a_dst1, es1, ed1, N * 4);

    // --- CSR build: hist -> scan -> partition -> finalize (writes ptr/csr/w1) ---
    hist_kernel<<<nblk, 256, 0, stream>>>(dst, E, Etot, nb, nblk, chunk, cnt);
    scanA_kernel<<<nbA, 1024, 0, stream>>>(cnt, bsum, M);
    scanB_kernel<<<1, 256, 0, stream>>>(bsum, nbA);
    partition_kernel<<<nblk, 256, 0, stream>>>(src, dst, E, Etot, nb, nblk, chunk,
                                               cnt, bsum, bkt);
    finalize_kernel<<<nb, 256, 0, stream>>>(bkt, cnt, bsum, nb, nblk, es1, ed1,
                                            ptr, csr, w1, N, Etot);

    // --- Layer 1 aggregate ---
    agg1_kernel<<<(N + 3) / 4, 256, 0, stream>>>((const unsigned int*)h1b, w1, csr, ptr,
                                                 b1, (unsigned int*)h1e, N);

    // --- Layer 2 ---
    gemm2_mfma_kernel<<<(N + 63) / 64, 256, 0, stream>>>(h1e, W2, h2b, N);
    dots2_kernel<<<(N + 255) / 256, 256, 0, stream>>>(h2b, a_src2, a_dst2, es2, ed2, N);
    weights2_kernel<<<(Etot + 255) / 256, 256, 0, stream>>>(csr, es2, ed2, w2, Etot);
    agg2_kernel<<<(N + 15) / 16, 256, 0, stream>>>((const unsigned int*)h2b, w2, csr, ptr,
                                                   b2, outp, N);
}

// Round 7
// 217.349 us; speedup vs baseline: 2.3967x; 1.0575x over previous
//
#include <hip/hip_runtime.h>
#include <hip/hip_bf16.h>

#define LRELU_SLOPE 0.2f
#define NB_SHIFT 7          // 128 dst-nodes per bucket

typedef __attribute__((ext_vector_type(8))) short short8;
typedef __attribute__((ext_vector_type(4))) float float4v;

// bf16 <-> fp32 helpers (raw ushort storage)
__device__ inline float b2f(unsigned short u) {
    union { unsigned int i; float f; } v; v.i = ((unsigned int)u) << 16; return v.f;
}
__device__ inline unsigned short f2b(float f) {
    union { float f; unsigned int i; } v; v.f = f;
    unsigned int x = v.i;
    unsigned int r = x + 0x7fffu + ((x >> 16) & 1u);   // round-to-nearest-even
    return (unsigned short)(r >> 16);
}
__device__ inline float lrelu(float x) { return x > 0.f ? x : LRELU_SLOPE * x; }

// ---------------------------------------------------------------------------
// CSR build, pass 1: per-block bucket histogram.  cnt[bucket*nblk + block]
// ---------------------------------------------------------------------------
__global__ __launch_bounds__(256) void hist_kernel(const int* __restrict__ dst,
                                                   int E, int Etot, int nb, int nblk,
                                                   int chunk, int* __restrict__ cnt) {
    __shared__ int hist[512];
    int blk = blockIdx.x;
    for (int i = threadIdx.x; i < nb; i += 256) hist[i] = 0;
    __syncthreads();
    int lo = blk * chunk;
    int hi = lo + chunk; if (hi > Etot) hi = Etot;
    for (int i = lo + threadIdx.x; i < hi; i += 256) {
        int d = (i < E) ? dst[i] : (i - E);
        atomicAdd(&hist[d >> NB_SHIFT], 1);
    }
    __syncthreads();
    for (int b = threadIdx.x; b < nb; b += 256)
        cnt[b * nblk + blk] = hist[b];
}

// in-place block-local exclusive scan (1024/block) + block totals
__global__ __launch_bounds__(1024) void scanA_kernel(int* cnt, int* bsum, int M) {
    __shared__ int tile[1024];
    int i = blockIdx.x * 1024 + threadIdx.x;
    int v = (i < M) ? cnt[i] : 0;
    tile[threadIdx.x] = v;
    __syncthreads();
    for (int off = 1; off < 1024; off <<= 1) {
        int t = (threadIdx.x >= (unsigned)off) ? tile[threadIdx.x - off] : 0;
        __syncthreads();
        tile[threadIdx.x] += t;
        __syncthreads();
    }
    int incl = tile[threadIdx.x];
    if (i < M) cnt[i] = incl - v;
    if (threadIdx.x == 1023) bsum[blockIdx.x] = incl;
}

__global__ __launch_bounds__(256) void scanB_kernel(int* __restrict__ bsum, int nb) {
    __shared__ int tile[256];
    int v = (threadIdx.x < (unsigned)nb) ? bsum[threadIdx.x] : 0;
    tile[threadIdx.x] = v;
    __syncthreads();
    for (int off = 1; off < 256; off <<= 1) {
        int t = (threadIdx.x >= (unsigned)off) ? tile[threadIdx.x - off] : 0;
        __syncthreads();
        tile[threadIdx.x] += t;
        __syncthreads();
    }
    if (threadIdx.x < (unsigned)nb) bsum[threadIdx.x] = tile[threadIdx.x] - v;
}

// ---------------------------------------------------------------------------
// CSR build, pass 2: partition edges into bucket array (no global atomics).
// ---------------------------------------------------------------------------
__global__ __launch_bounds__(256) void partition_kernel(
        const int* __restrict__ src, const int* __restrict__ dst,
        int E, int Etot, int nb, int nblk, int chunk,
        const int* __restrict__ cnt, const int* __restrict__ boff,
        int2* __restrict__ bkt) {
    __shared__ int cur[512];
    int blk = blockIdx.x;
    for (int b = threadIdx.x; b < nb; b += 256) {
        int idx = b * nblk + blk;
        cur[b] = cnt[idx] + boff[idx >> 10];
    }
    __syncthreads();
    int lo = blk * chunk;
    int hi = lo + chunk; if (hi > Etot) hi = Etot;
    for (int i = lo + threadIdx.x; i < hi; i += 256) {
        int s, d;
        if (i < E) { s = src[i]; d = dst[i]; }
        else       { s = d = i - E; }
        int pos = atomicAdd(&cur[d >> NB_SHIFT], 1);
        bkt[pos] = make_int2(s, d);
    }
}

// ---------------------------------------------------------------------------
// CSR build, pass 3 (one block per bucket): degree count -> LDS scan -> ptr;
// place src indices at final CSR positions; fold in layer-1 edge weights.
// ---------------------------------------------------------------------------
__global__ __launch_bounds__(256) void finalize_kernel(
        const int2* __restrict__ bkt, const int* __restrict__ cnt,
        const int* __restrict__ boff, int nb, int nblk,
        const float* __restrict__ es, const float* __restrict__ ed,
        int* __restrict__ ptr, int* __restrict__ csr_src, float* __restrict__ w1,
        int N, int Etot) {
    __shared__ int deg[128];
    __shared__ int scn[128];
    __shared__ int cur[128];
    int b = blockIdx.x;
    int idx0 = b * nblk;
    int base = cnt[idx0] + boff[idx0 >> 10];
    int nextbase;
    if (b + 1 < nb) {
        int idx1 = (b + 1) * nblk;
        nextbase = cnt[idx1] + boff[idx1 >> 10];
    } else nextbase = Etot;
    int count = nextbase - base;
    int node0 = b << NB_SHIFT;
    int nodes = N - node0; if (nodes > 128) nodes = 128;

    if (threadIdx.x < 128) deg[threadIdx.x] = 0;
    __syncthreads();
    for (int i = threadIdx.x; i < count; i += 256)
        atomicAdd(&deg[bkt[base + i].y - node0], 1);
    __syncthreads();
    int v = (threadIdx.x < 128) ? deg[threadIdx.x] : 0;
    if (threadIdx.x < 128) scn[threadIdx.x] = v;
    __syncthreads();
    for (int off = 1; off < 128; off <<= 1) {
        int t = (threadIdx.x < 128 && threadIdx.x >= (unsigned)off) ? scn[threadIdx.x - off] : 0;
        __syncthreads();
        if (threadIdx.x < 128) scn[threadIdx.x] += t;
        __syncthreads();
    }
    if (threadIdx.x < 128) {
        int excl = scn[threadIdx.x] - v;
        cur[threadIdx.x] = excl;
        if (threadIdx.x < nodes) ptr[node0 + threadIdx.x] = base + excl;
    }
    if (b == nb - 1 && threadIdx.x == 0) ptr[N] = Etot;
    __syncthreads();
    for (int i = threadIdx.x; i < count; i += 256) {
        int2 sd = bkt[base + i];
        int pos = base + atomicAdd(&cur[sd.y - node0], 1);
        csr_src[pos] = sd.x;
        float4 a = *(const float4*)&es[sd.x * 4];
        float4 bb = *(const float4*)&ed[sd.y * 4];
        float4 ww;
        ww.x = __expf(lrelu(a.x + bb.x));
        ww.y = __expf(lrelu(a.y + bb.y));
        ww.z = __expf(lrelu(a.z + bb.z));
        ww.w = __expf(lrelu(a.w + bb.w));
        *(float4*)&w1[(size_t)pos * 4] = ww;
    }
}

// ---------------------------------------------------------------------------
// GEMM1 (MFMA bf16) + fused dots1: h1b = bf16(x @ W1); es/ed per (row,head)
// computed from the bf16 tile staged back into LDS (identical numerics to the
// old separate dots1 kernel which re-read h1b).
// ---------------------------------------------------------------------------
__global__ __launch_bounds__(256) void gemm1_mfma_kernel(
        const float* __restrict__ x, const float* __restrict__ W1,
        const float* __restrict__ a_src, const float* __restrict__ a_dst,
        unsigned short* __restrict__ h1b, float* __restrict__ es,
        float* __restrict__ ed, int N) {
    __shared__ unsigned short xs[64][136];
    __shared__ unsigned short wt[128][136];
    int tid = threadIdx.x;
    int n0 = blockIdx.x * 64;

    for (int i = tid; i < 128 * 128; i += 256) {
        int k = i >> 7, n = i & 127;
        wt[n][k] = f2b(W1[i]);
    }
    for (int i = tid; i < 64 * 128; i += 256) {
        int r = i >> 7, k = i & 127;
        int row = n0 + r; if (row >= N) row = N - 1;
        xs[r][k] = f2b(x[(size_t)row * 128 + k]);
    }
    __syncthreads();

    int wave = tid >> 6;
    int lane = tid & 63;
    int lrow = lane & 15;
    int quad = lane >> 4;

    short8 afr[4];
#pragma unroll
    for (int kc = 0; kc < 4; kc++)
        afr[kc] = *(const short8*)&xs[wave * 16 + lrow][kc * 32 + quad * 8];
    __syncthreads();   // all waves' A-fragment reads done before xs is reused

#pragma unroll
    for (int ct = 0; ct < 8; ct++) {
        float4v acc = {0.f, 0.f, 0.f, 0.f};
#pragma unroll
        for (int kc = 0; kc < 4; kc++) {
            short8 bfr = *(const short8*)&wt[ct * 16 + lrow][kc * 32 + quad * 8];
            acc = __builtin_amdgcn_mfma_f32_16x16x32_bf16(afr[kc], bfr, acc, 0, 0, 0);
        }
#pragma unroll
        for (int r = 0; r < 4; r++) {
            int lr = wave * 16 + quad * 4 + r;
            int grow = n0 + lr;
            unsigned short hb = f2b(acc[r]);
            xs[lr][ct * 16 + lrow] = hb;           // stage result tile for dots
            if (grow < N)
                h1b[grow * 128 + ct * 16 + lrow] = hb;
        }
    }
    __syncthreads();

    // fused dots1: thread = (row, head); 32-channel dot per head
    int row = tid >> 2, h = tid & 3;
    int rg = n0 + row;
    if (rg < N) {
        const float* ap = a_src + h * 32;
        const float* bp = a_dst + h * 32;
        float s = 0.f, d = 0.f;
#pragma unroll
        for (int c2 = 0; c2 < 16; c2++) {
            unsigned int u = *(const unsigned int*)&xs[row][h * 32 + 2 * c2];
            float v0 = b2f((unsigned short)(u & 0xffffu));
            float v1 = b2f((unsigned short)(u >> 16));
            float2 a = *(const float2*)&ap[2 * c2];
            float2 b = *(const float2*)&bp[2 * c2];
            s += v0 * a.x + v1 * a.y;
            d += v0 * b.x + v1 * b.y;
        }
        es[rg * 4 + h] = s;
        ed[rg * 4 + h] = d;
    }
}

// ---------------------------------------------------------------------------
// GEMM2 (MFMA bf16) + fused dots2: h2b = bf16(h1e @ W2); es2/ed2 per row.
// ---------------------------------------------------------------------------
__global__ __launch_bounds__(256) void gemm2_mfma_kernel(
        const unsigned short* __restrict__ h1e, const float* __restrict__ W2,
        const float* __restrict__ a_src, const float* __restrict__ a_dst,
        unsigned short* __restrict__ h2b, float* __restrict__ es,
        float* __restrict__ ed, int N) {
    __shared__ unsigned short xs[64][136];
    __shared__ unsigned short wt[32][136];
    int tid = threadIdx.x;
    int n0 = blockIdx.x * 64;

    for (int i = tid; i < 128 * 32; i += 256) {
        int k = i >> 5, n = i & 31;
        wt[n][k] = f2b(W2[i]);
    }
    {
        const unsigned int* srcp = (const unsigned int*)(h1e + (size_t)n0 * 128);
        int rows = (N - n0) < 64 ? (N - n0) : 64;
        int maxu = rows * 64;
        for (int i = tid; i < 4096; i += 256) {
            unsigned int v = (i < maxu) ? srcp[i] : 0u;
            int r = i >> 6, cp = (i & 63) << 1;
            *(unsigned int*)&xs[r][cp] = v;
        }
    }
    __syncthreads();

    int wave = tid >> 6;
    int lane = tid & 63;
    int lrow = lane & 15;
    int quad = lane >> 4;

    short8 afr[4];
#pragma unroll
    for (int kc = 0; kc < 4; kc++)
        afr[kc] = *(const short8*)&xs[wave * 16 + lrow][kc * 32 + quad * 8];
    __syncthreads();

#pragma unroll
    for (int ct = 0; ct < 2; ct++) {
        float4v acc = {0.f, 0.f, 0.f, 0.f};
#pragma unroll
        for (int kc = 0; kc < 4; kc++) {
            short8 bfr = *(const short8*)&wt[ct * 16 + lrow][kc * 32 + quad * 8];
            acc = __builtin_amdgcn_mfma_f32_16x16x32_bf16(afr[kc], bfr, acc, 0, 0, 0);
        }
#pragma unroll
        for (int r = 0; r < 4; r++) {
            int lr = wave * 16 + quad * 4 + r;
            int grow = n0 + lr;
            unsigned short hb = f2b(acc[r]);
            xs[lr][ct * 16 + lrow] = hb;
            if (grow < N)
                h2b[(size_t)grow * 32 + ct * 16 + lrow] = hb;
        }
    }
    __syncthreads();

    // fused dots2 (1 head, 32 channels): threads 0..63 = rows
    if (tid < 64) {
        int rg = n0 + tid;
        if (rg < N) {
            float s = 0.f, d = 0.f;
#pragma unroll
            for (int c2 = 0; c2 < 16; c2++) {
                unsigned int u = *(const unsigned int*)&xs[tid][2 * c2];
                float v0 = b2f((unsigned short)(u & 0xffffu));
                float v1 = b2f((unsigned short)(u >> 16));
                float2 a = *(const float2*)&a_src[2 * c2];
                float2 b = *(const float2*)&a_dst[2 * c2];
                s += v0 * a.x + v1 * a.y;
                d += v0 * b.x + v1 * b.y;
            }
            es[rg] = s;
            ed[rg] = d;
        }
    }
}

// ---------------------------------------------------------------------------
// Aggregation layer 1: one node per WAVE (64 lanes x 2 packed-bf16 channels),
// unrolled x8 for deeper MLP (latency-bound gather loop).
// ---------------------------------------------------------------------------
__global__ __launch_bounds__(256) void agg1_kernel(
        const unsigned int* __restrict__ h1u, const float* __restrict__ w1,
        const int* __restrict__ csr, const int* __restrict__ ptr,
        const float* __restrict__ b1, unsigned int* __restrict__ h1e_u, int N) {
    int wave = threadIdx.x >> 6;
    int lane = threadIdx.x & 63;
    int n = blockIdx.x * 4 + wave;
    if (n >= N) return;
    int h = lane >> 4;
    int start = ptr[n], end = ptr[n + 1];
    float acc0 = 0.f, acc1 = 0.f, wsum = 0.f;
    int i = start;
    for (; i + 8 <= end; i += 8) {
        int s[8]; float v[8]; unsigned int g[8];
#pragma unroll
        for (int k = 0; k < 8; k++) s[k] = csr[i + k];
#pragma unroll
        for (int k = 0; k < 8; k++) v[k] = w1[(size_t)(i + k) * 4 + h];
#pragma unroll
        for (int k = 0; k < 8; k++) g[k] = h1u[(s[k] << 6) + lane];
#pragma unroll
        for (int k = 0; k < 8; k++) {
            acc0 += v[k] * b2f((unsigned short)(g[k] & 0xffffu));
            acc1 += v[k] * b2f((unsigned short)(g[k] >> 16));
            wsum += v[k];
        }
    }
    for (; i + 4 <= end; i += 4) {
        int s[4]; float v[4]; unsigned int g[4];
#pragma unroll
        for (int k = 0; k < 4; k++) s[k] = csr[i + k];
#pragma unroll
        for (int k = 0; k < 4; k++) v[k] = w1[(size_t)(i + k) * 4 + h];
#pragma unroll
        for (int k = 0; k < 4; k++) g[k] = h1u[(s[k] << 6) + lane];
#pragma unroll
        for (int k = 0; k < 4; k++) {
            acc0 += v[k] * b2f((unsigned short)(g[k] & 0xffffu));
            acc1 += v[k] * b2f((unsigned short)(g[k] >> 16));
            wsum += v[k];
        }
    }
    for (; i < end; i++) {
        int s = csr[i];
        float v = w1[(size_t)i * 4 + h];
        unsigned int g = h1u[(s << 6) + lane];
        acc0 += v * b2f((unsigned short)(g & 0xffffu));
        acc1 += v * b2f((unsigned short)(g >> 16));
        wsum += v;
    }
    float r = 1.f / wsum;
    float2 bb = ((const float2*)b1)[lane];
    float o0 = acc0 * r + bb.x;
    float o1 = acc1 * r + bb.y;
    o0 = o0 > 0.f ? o0 : __expf(o0) - 1.f;
    o1 = o1 > 0.f ? o1 : __expf(o1) - 1.f;
    h1e_u[(n << 6) + lane] = (unsigned int)f2b(o0) | ((unsigned int)f2b(o1) << 16);
}

// ---------------------------------------------------------------------------
// Aggregation layer 2: 16 lanes/node x 2 packed-bf16 channels; edge weight
// (exp(lrelu(es[s]+ed[n]))) computed inline — no weights2 kernel/stream.
// ---------------------------------------------------------------------------
__global__ __launch_bounds__(256) void agg2_kernel(
        const unsigned int* __restrict__ h2u, const float* __restrict__ es,
        const float* __restrict__ ed, const int* __restrict__ csr,
        const int* __restrict__ ptr, const float* __restrict__ b2,
        float* __restrict__ out, int N) {
    int lane = threadIdx.x & 63;
    int n = blockIdx.x * 16 + (threadIdx.x >> 6) * 4 + (lane >> 4);
    if (n >= N) return;
    int cl = lane & 15;
    float edl = ed[n];
    int start = ptr[n], end = ptr[n + 1];
    float acc0 = 0.f, acc1 = 0.f, wsum = 0.f;
    int i = start;
    for (; i + 4 <= end; i += 4) {
        int s[4]; float e[4]; unsigned int g[4];
#pragma unroll
        for (int k = 0; k < 4; k++) s[k] = csr[i + k];
#pragma unroll
        for (int k = 0; k < 4; k++) e[k] = es[s[k]];
#pragma unroll
        for (int k = 0; k < 4; k++) g[k] = h2u[(s[k] << 4) + cl];
#pragma unroll
        for (int k = 0; k < 4; k++) {
            float v = __expf(lrelu(e[k] + edl));
            acc0 += v * b2f((unsigned short)(g[k] & 0xffffu));
            acc1 += v * b2f((unsigned short)(g[k] >> 16));
            wsum += v;
        }
    }
    for (; i < end; i++) {
        int s = csr[i];
        float v = __expf(lrelu(es[s] + edl));
        unsigned int g = h2u[(s << 4) + cl];
        acc0 += v * b2f((unsigned short)(g & 0xffffu));
        acc1 += v * b2f((unsigned short)(g >> 16));
        wsum += v;
    }
    float r = 1.f / wsum;
    float2 bb = ((const float2*)b2)[cl];
    float2 o;
    o.x = acc0 * r + bb.x;
    o.y = acc1 * r + bb.y;
    ((float2*)out)[(size_t)n * 16 + cl] = o;
}

// ---------------------------------------------------------------------------
extern "C" void kernel_launch(void* const* d_in, const int* in_sizes, int n_in,
                              void* d_out, int out_size, void* d_ws, size_t ws_size,
                              hipStream_t stream) {
    const float* x      = (const float*)d_in[0];
    const int*   ei     = (const int*)  d_in[1];
    const float* W1     = (const float*)d_in[2];
    const float* a_src1 = (const float*)d_in[3];
    const float* a_dst1 = (const float*)d_in[4];
    const float* b1     = (const float*)d_in[5];
    const float* W2     = (const float*)d_in[6];
    const float* a_src2 = (const float*)d_in[7];
    const float* a_dst2 = (const float*)d_in[8];
    const float* b2     = (const float*)d_in[9];
    float* outp = (float*)d_out;

    const int N = in_sizes[0] / 128;   // 50000
    const int E = in_sizes[1] / 2;     // 800000
    const int Etot = E + N;            // 850000

    const int* src = ei;
    const int* dst = ei + E;

    const int nb   = (N + 127) >> 7;                 // 391 buckets
    const int nblk = 128;                            // hist/partition blocks
    const int chunk = (Etot + nblk - 1) / nblk;      // 6641
    const int M = nb * nblk;                         // 50048 scan elements
    const int nbA = (M + 1023) / 1024;               // 49

    // workspace layout (bytes); total ~55.0 MB
    char* w = (char*)d_ws;
    unsigned short* h1b = (unsigned short*)(w + 0);          // 12,800,000
    unsigned short* h1e = (unsigned short*)(w + 12800000);   // 12,800,000
    unsigned short* h2b = (unsigned short*)(w + 25600000);   //  3,200,000
    float* es1  = (float*)(w + 28800000);                    //    800,000
    float* ed1  = (float*)(w + 29600000);                    //    800,000
    float* es2  = (float*)(w + 30400000);                    //    200,000
    float* ed2  = (float*)(w + 30600000);                    //    200,000
    int*   ptr  = (int*)  (w + 30800000);                    //    200,064
    int*   bsum = (int*)  (w + 31000064);                    //      1,024
    int*   cnt  = (int*)  (w + 31001088);                    //    200,192
    int*   csr_src = (int*)(w + 31201280);                   //  3,400,000
    int2*  bkt  = (int2*) (w + 34601280);                    //  6,800,000
    float* w1   = (float*)(w + 41401280);                    // 13,600,000 -> 55,001,280

    // --- Layer-1 GEMM + fused logit dots (CSR-independent) ---
    gemm1_mfma_kernel<<<(N + 63) / 64, 256, 0, stream>>>(x, W1, a_src1, a_dst1,
                                                         h1b, es1, ed1, N);

    // --- CSR build: hist -> scan -> partition -> finalize (ptr/csr_src/w1) ---
    hist_kernel<<<nblk, 256, 0, stream>>>(dst, E, Etot, nb, nblk, chunk, cnt);
    scanA_kernel<<<nbA, 1024, 0, stream>>>(cnt, bsum, M);
    scanB_kernel<<<1, 256, 0, stream>>>(bsum, nbA);
    partition_kernel<<<nblk, 256, 0, stream>>>(src, dst, E, Etot, nb, nblk, chunk,
                                               cnt, bsum, bkt);
    finalize_kernel<<<nb, 256, 0, stream>>>(bkt, cnt, bsum, nb, nblk, es1, ed1,
                                            ptr, csr_src, w1, N, Etot);

    // --- Layer 1 aggregate ---
    agg1_kernel<<<(N + 3) / 4, 256, 0, stream>>>((const unsigned int*)h1b, w1,
                                                 csr_src, ptr, b1,
                                                 (unsigned int*)h1e, N);

    // --- Layer 2: GEMM + fused dots, then aggregate with inline weights ---
    gemm2_mfma_kernel<<<(N + 63) / 64, 256, 0, stream>>>(h1e, W2, a_src2, a_dst2,
                                                         h2b, es2, ed2, N);
    agg2_kernel<<<(N + 15) / 16, 256, 0, stream>>>((const unsigned int*)h2b, es2, ed2,
                                                   csr_src, ptr, b2, outp, N);
}

// Round 8
// 201.046 us; speedup vs baseline: 2.5910x; 1.0811x over previous
//
#include <hip/hip_runtime.h>
#include <hip/hip_bf16.h>

#define LRELU_SLOPE 0.2f
#define NB_SHIFT 7          // 128 dst-nodes per bucket
#define NBLK 512            // hist/partition parallel chunks

typedef __attribute__((ext_vector_type(8))) short short8;
typedef __attribute__((ext_vector_type(4))) float float4v;

// bf16 <-> fp32 helpers (raw ushort storage)
__device__ inline float b2f(unsigned short u) {
    union { unsigned int i; float f; } v; v.i = ((unsigned int)u) << 16; return v.f;
}
__device__ inline unsigned short f2b(float f) {
    union { float f; unsigned int i; } v; v.f = f;
    unsigned int x = v.i;
    unsigned int r = x + 0x7fffu + ((x >> 16) & 1u);   // round-to-nearest-even
    return (unsigned short)(r >> 16);
}
__device__ inline float lrelu(float x) { return x > 0.f ? x : LRELU_SLOPE * x; }

// ---------------------------------------------------------------------------
// GEMM1 (MFMA bf16) + fused dots1 + fused CSR hist (blocks < NBLK).
// h1b = bf16(x @ W1); es/ed per (row,head); cnt[bucket*NBLK+blk] histogram.
// ---------------------------------------------------------------------------
__global__ __launch_bounds__(256) void gemm1_mfma_kernel(
        const float* __restrict__ x, const float* __restrict__ W1,
        const float* __restrict__ a_src, const float* __restrict__ a_dst,
        unsigned short* __restrict__ h1b, float* __restrict__ es,
        float* __restrict__ ed, int N,
        const int* __restrict__ dst, int E, int Etot, int nb, int chunk,
        int* __restrict__ cnt) {
    __shared__ unsigned short xs[64][136];
    __shared__ unsigned short wt[128][136];
    int tid = threadIdx.x;
    int n0 = blockIdx.x * 64;

    for (int i = tid; i < 128 * 128; i += 256) {
        int k = i >> 7, n = i & 127;
        wt[n][k] = f2b(W1[i]);
    }
    for (int i = tid; i < 64 * 128; i += 256) {
        int r = i >> 7, k = i & 127;
        int row = n0 + r; if (row >= N) row = N - 1;
        xs[r][k] = f2b(x[(size_t)row * 128 + k]);
    }
    __syncthreads();

    int wave = tid >> 6;
    int lane = tid & 63;
    int lrow = lane & 15;
    int quad = lane >> 4;

    short8 afr[4];
#pragma unroll
    for (int kc = 0; kc < 4; kc++)
        afr[kc] = *(const short8*)&xs[wave * 16 + lrow][kc * 32 + quad * 8];
    __syncthreads();   // all waves' A-fragment reads done before xs is reused

#pragma unroll
    for (int ct = 0; ct < 8; ct++) {
        float4v acc = {0.f, 0.f, 0.f, 0.f};
#pragma unroll
        for (int kc = 0; kc < 4; kc++) {
            short8 bfr = *(const short8*)&wt[ct * 16 + lrow][kc * 32 + quad * 8];
            acc = __builtin_amdgcn_mfma_f32_16x16x32_bf16(afr[kc], bfr, acc, 0, 0, 0);
        }
#pragma unroll
        for (int r = 0; r < 4; r++) {
            int lr = wave * 16 + quad * 4 + r;
            int grow = n0 + lr;
            unsigned short hb = f2b(acc[r]);
            xs[lr][ct * 16 + lrow] = hb;           // stage result tile for dots
            if (grow < N)
                h1b[grow * 128 + ct * 16 + lrow] = hb;
        }
    }
    __syncthreads();   // xs result tile ready; wt reads done (reused below)

    // fused dots1: thread = (row, head); 32-channel dot per head
    int row = tid >> 2, h = tid & 3;
    int rg = n0 + row;
    if (rg < N) {
        const float* ap = a_src + h * 32;
        const float* bp = a_dst + h * 32;
        float s = 0.f, d = 0.f;
#pragma unroll
        for (int c2 = 0; c2 < 16; c2++) {
            unsigned int u = *(const unsigned int*)&xs[row][h * 32 + 2 * c2];
            float v0 = b2f((unsigned short)(u & 0xffffu));
            float v1 = b2f((unsigned short)(u >> 16));
            float2 a = *(const float2*)&ap[2 * c2];
            float2 b = *(const float2*)&bp[2 * c2];
            s += v0 * a.x + v1 * a.y;
            d += v0 * b.x + v1 * b.y;
        }
        es[rg * 4 + h] = s;
        ed[rg * 4 + h] = d;
    }

    // fused CSR histogram (reuses wt LDS; all threads hit the barriers)
    int* histm = (int*)&wt[0][0];
    int blk = blockIdx.x;
    if (blk < NBLK)
        for (int i = tid; i < nb; i += 256) histm[i] = 0;
    __syncthreads();
    if (blk < NBLK) {
        int lo = blk * chunk;
        int hi = lo + chunk; if (hi > Etot) hi = Etot;
        for (int i = lo + tid; i < hi; i += 256) {
            int d = (i < E) ? dst[i] : (i - E);
            atomicAdd(&histm[d >> NB_SHIFT], 1);
        }
    }
    __syncthreads();
    if (blk < NBLK)
        for (int b = tid; b < nb; b += 256)
            cnt[b * NBLK + blk] = histm[b];
}

// in-place block-local exclusive scan (1024/block) + block totals
__global__ __launch_bounds__(1024) void scanA_kernel(int* cnt, int* bsum, int M) {
    __shared__ int tile[1024];
    int i = blockIdx.x * 1024 + threadIdx.x;
    int v = (i < M) ? cnt[i] : 0;
    tile[threadIdx.x] = v;
    __syncthreads();
    for (int off = 1; off < 1024; off <<= 1) {
        int t = (threadIdx.x >= (unsigned)off) ? tile[threadIdx.x - off] : 0;
        __syncthreads();
        tile[threadIdx.x] += t;
        __syncthreads();
    }
    int incl = tile[threadIdx.x];
    if (i < M) cnt[i] = incl - v;
    if (threadIdx.x == 1023) bsum[blockIdx.x] = incl;
}

__global__ __launch_bounds__(256) void scanB_kernel(int* __restrict__ bsum, int nb) {
    __shared__ int tile[256];
    int v = (threadIdx.x < (unsigned)nb) ? bsum[threadIdx.x] : 0;
    tile[threadIdx.x] = v;
    __syncthreads();
    for (int off = 1; off < 256; off <<= 1) {
        int t = (threadIdx.x >= (unsigned)off) ? tile[threadIdx.x - off] : 0;
        __syncthreads();
        tile[threadIdx.x] += t;
        __syncthreads();
    }
    if (threadIdx.x < (unsigned)nb) bsum[threadIdx.x] = tile[threadIdx.x] - v;
}

// ---------------------------------------------------------------------------
// CSR build, pass 2: partition edges into bucket array (no global atomics).
// ---------------------------------------------------------------------------
__global__ __launch_bounds__(256) void partition_kernel(
        const int* __restrict__ src, const int* __restrict__ dst,
        int E, int Etot, int nb, int chunk,
        const int* __restrict__ cnt, const int* __restrict__ boff,
        int2* __restrict__ bkt) {
    __shared__ int cur[512];
    int blk = blockIdx.x;
    for (int b = threadIdx.x; b < nb; b += 256) {
        int idx = b * NBLK + blk;
        cur[b] = cnt[idx] + boff[idx >> 10];
    }
    __syncthreads();
    int lo = blk * chunk;
    int hi = lo + chunk; if (hi > Etot) hi = Etot;
    for (int i = lo + threadIdx.x; i < hi; i += 256) {
        int s, d;
        if (i < E) { s = src[i]; d = dst[i]; }
        else       { s = d = i - E; }
        int pos = atomicAdd(&cur[d >> NB_SHIFT], 1);
        bkt[pos] = make_int2(s, d);
    }
}

// ---------------------------------------------------------------------------
// CSR build, pass 3 (one block per bucket): degree count -> LDS scan -> ptr;
// place src indices at final CSR positions; fold in fp16 layer-1 edge weights.
// ---------------------------------------------------------------------------
__global__ __launch_bounds__(256) void finalize_kernel(
        const int2* __restrict__ bkt, const int* __restrict__ cnt,
        const int* __restrict__ boff, int nb,
        const float* __restrict__ es, const float* __restrict__ ed,
        int* __restrict__ ptr, int* __restrict__ csr_src,
        _Float16* __restrict__ w1h, int N, int Etot) {
    __shared__ int deg[128];
    __shared__ int scn[128];
    __shared__ int cur[128];
    int b = blockIdx.x;
    int idx0 = b * NBLK;
    int base = cnt[idx0] + boff[idx0 >> 10];
    int nextbase;
    if (b + 1 < nb) {
        int idx1 = (b + 1) * NBLK;
        nextbase = cnt[idx1] + boff[idx1 >> 10];
    } else nextbase = Etot;
    int count = nextbase - base;
    int node0 = b << NB_SHIFT;
    int nodes = N - node0; if (nodes > 128) nodes = 128;

    if (threadIdx.x < 128) deg[threadIdx.x] = 0;
    __syncthreads();
    for (int i = threadIdx.x; i < count; i += 256)
        atomicAdd(&deg[bkt[base + i].y - node0], 1);
    __syncthreads();
    int v = (threadIdx.x < 128) ? deg[threadIdx.x] : 0;
    if (threadIdx.x < 128) scn[threadIdx.x] = v;
    __syncthreads();
    for (int off = 1; off < 128; off <<= 1) {
        int t = (threadIdx.x < 128 && threadIdx.x >= (unsigned)off) ? scn[threadIdx.x - off] : 0;
        __syncthreads();
        if (threadIdx.x < 128) scn[threadIdx.x] += t;
        __syncthreads();
    }
    if (threadIdx.x < 128) {
        int excl = scn[threadIdx.x] - v;
        cur[threadIdx.x] = excl;
        if (threadIdx.x < nodes) ptr[node0 + threadIdx.x] = base + excl;
    }
    if (b == nb - 1 && threadIdx.x == 0) ptr[N] = Etot;
    __syncthreads();
    for (int i = threadIdx.x; i < count; i += 256) {
        int2 sd = bkt[base + i];
        int pos = base + atomicAdd(&cur[sd.y - node0], 1);
        csr_src[pos] = sd.x;
        float4 a = *(const float4*)&es[sd.x * 4];
        float4 bb = *(const float4*)&ed[sd.y * 4];
        union { _Float16 h[4]; uint2 u; } ww;
        ww.h[0] = (_Float16)__expf(lrelu(a.x + bb.x));
        ww.h[1] = (_Float16)__expf(lrelu(a.y + bb.y));
        ww.h[2] = (_Float16)__expf(lrelu(a.z + bb.z));
        ww.h[3] = (_Float16)__expf(lrelu(a.w + bb.w));
        *(uint2*)&w1h[(size_t)pos * 4] = ww.u;
    }
}

// ---------------------------------------------------------------------------
// GEMM2 (MFMA bf16) + fused dots2: h2b = bf16(h1e @ W2); es2/ed2 per row.
// ---------------------------------------------------------------------------
__global__ __launch_bounds__(256) void gemm2_mfma_kernel(
        const unsigned short* __restrict__ h1e, const float* __restrict__ W2,
        const float* __restrict__ a_src, const float* __restrict__ a_dst,
        unsigned short* __restrict__ h2b, float* __restrict__ es,
        float* __restrict__ ed, int N) {
    __shared__ unsigned short xs[64][136];
    __shared__ unsigned short wt[32][136];
    int tid = threadIdx.x;
    int n0 = blockIdx.x * 64;

    for (int i = tid; i < 128 * 32; i += 256) {
        int k = i >> 5, n = i & 31;
        wt[n][k] = f2b(W2[i]);
    }
    {
        const unsigned int* srcp = (const unsigned int*)(h1e + (size_t)n0 * 128);
        int rows = (N - n0) < 64 ? (N - n0) : 64;
        int maxu = rows * 64;
        for (int i = tid; i < 4096; i += 256) {
            unsigned int v = (i < maxu) ? srcp[i] : 0u;
            int r = i >> 6, cp = (i & 63) << 1;
            *(unsigned int*)&xs[r][cp] = v;
        }
    }
    __syncthreads();

    int wave = tid >> 6;
    int lane = tid & 63;
    int lrow = lane & 15;
    int quad = lane >> 4;

    short8 afr[4];
#pragma unroll
    for (int kc = 0; kc < 4; kc++)
        afr[kc] = *(const short8*)&xs[wave * 16 + lrow][kc * 32 + quad * 8];
    __syncthreads();

#pragma unroll
    for (int ct = 0; ct < 2; ct++) {
        float4v acc = {0.f, 0.f, 0.f, 0.f};
#pragma unroll
        for (int kc = 0; kc < 4; kc++) {
            short8 bfr = *(const short8*)&wt[ct * 16 + lrow][kc * 32 + quad * 8];
            acc = __builtin_amdgcn_mfma_f32_16x16x32_bf16(afr[kc], bfr, acc, 0, 0, 0);
        }
#pragma unroll
        for (int r = 0; r < 4; r++) {
            int lr = wave * 16 + quad * 4 + r;
            int grow = n0 + lr;
            unsigned short hb = f2b(acc[r]);
            xs[lr][ct * 16 + lrow] = hb;
            if (grow < N)
                h2b[(size_t)grow * 32 + ct * 16 + lrow] = hb;
        }
    }
    __syncthreads();

    // fused dots2 (1 head, 32 channels): threads 0..63 = rows
    if (tid < 64) {
        int rg = n0 + tid;
        if (rg < N) {
            float s = 0.f, d = 0.f;
#pragma unroll
            for (int c2 = 0; c2 < 16; c2++) {
                unsigned int u = *(const unsigned int*)&xs[tid][2 * c2];
                float v0 = b2f((unsigned short)(u & 0xffffu));
                float v1 = b2f((unsigned short)(u >> 16));
                float2 a = *(const float2*)&a_src[2 * c2];
                float2 b = *(const float2*)&a_dst[2 * c2];
                s += v0 * a.x + v1 * a.y;
                d += v0 * b.x + v1 * b.y;
            }
            es[rg] = s;
            ed[rg] = d;
        }
    }
}

// ---------------------------------------------------------------------------
// Aggregation layer 1: 32 lanes/node x 4 channels (uint2 = 4 bf16 per load),
// 2 nodes/wave, 8 nodes/block.  Halves gather-instruction count vs R7.
// ---------------------------------------------------------------------------
__global__ __launch_bounds__(256) void agg1_kernel(
        const uint2* __restrict__ h1v, const _Float16* __restrict__ w1h,
        const int* __restrict__ csr, const int* __restrict__ ptr,
        const float* __restrict__ b1, uint2* __restrict__ h1e_v, int N) {
    int tid = threadIdx.x;
    int n = blockIdx.x * 8 + (tid >> 5);
    if (n >= N) return;
    int cl = tid & 31;           // channel group: ch 4cl..4cl+3
    int h = cl >> 3;             // head
    int start = ptr[n], end = ptr[n + 1];
    float a0 = 0.f, a1 = 0.f, a2 = 0.f, a3 = 0.f, ws = 0.f;
    int i = start;
    for (; i + 8 <= end; i += 8) {
        int s[8]; float v[8]; uint2 g[8];
#pragma unroll
        for (int k = 0; k < 8; k++) s[k] = csr[i + k];
#pragma unroll
        for (int k = 0; k < 8; k++) v[k] = (float)w1h[(size_t)(i + k) * 4 + h];
#pragma unroll
        for (int k = 0; k < 8; k++) g[k] = h1v[(s[k] << 5) + cl];
#pragma unroll
        for (int k = 0; k < 8; k++) {
            a0 += v[k] * b2f((unsigned short)(g[k].x & 0xffffu));
            a1 += v[k] * b2f((unsigned short)(g[k].x >> 16));
            a2 += v[k] * b2f((unsigned short)(g[k].y & 0xffffu));
            a3 += v[k] * b2f((unsigned short)(g[k].y >> 16));
            ws += v[k];
        }
    }
    for (; i < end; i++) {
        int s = csr[i];
        float v = (float)w1h[(size_t)i * 4 + h];
        uint2 g = h1v[(s << 5) + cl];
        a0 += v * b2f((unsigned short)(g.x & 0xffffu));
        a1 += v * b2f((unsigned short)(g.x >> 16));
        a2 += v * b2f((unsigned short)(g.y & 0xffffu));
        a3 += v * b2f((unsigned short)(g.y >> 16));
        ws += v;
    }
    float r = 1.f / ws;
    float4 bb = ((const float4*)b1)[cl];
    float o0 = a0 * r + bb.x;
    float o1 = a1 * r + bb.y;
    float o2 = a2 * r + bb.z;
    float o3 = a3 * r + bb.w;
    o0 = o0 > 0.f ? o0 : __expf(o0) - 1.f;
    o1 = o1 > 0.f ? o1 : __expf(o1) - 1.f;
    o2 = o2 > 0.f ? o2 : __expf(o2) - 1.f;
    o3 = o3 > 0.f ? o3 : __expf(o3) - 1.f;
    uint2 outv;
    outv.x = (unsigned int)f2b(o0) | ((unsigned int)f2b(o1) << 16);
    outv.y = (unsigned int)f2b(o2) | ((unsigned int)f2b(o3) << 16);
    h1e_v[(n << 5) + cl] = outv;
}

// ---------------------------------------------------------------------------
// Aggregation layer 2: 16 lanes/node x 2 packed-bf16 channels; inline weights.
// ---------------------------------------------------------------------------
__global__ __launch_bounds__(256) void agg2_kernel(
        const unsigned int* __restrict__ h2u, const float* __restrict__ es,
        const float* __restrict__ ed, const int* __restrict__ csr,
        const int* __restrict__ ptr, const float* __restrict__ b2,
        float* __restrict__ out, int N) {
    int lane = threadIdx.x & 63;
    int n = blockIdx.x * 16 + (threadIdx.x >> 6) * 4 + (lane >> 4);
    if (n >= N) return;
    int cl = lane & 15;
    float edl = ed[n];
    int start = ptr[n], end = ptr[n + 1];
    float acc0 = 0.f, acc1 = 0.f, wsum = 0.f;
    int i = start;
    for (; i + 4 <= end; i += 4) {
        int s[4]; float e[4]; unsigned int g[4];
#pragma unroll
        for (int k = 0; k < 4; k++) s[k] = csr[i + k];
#pragma unroll
        for (int k = 0; k < 4; k++) e[k] = es[s[k]];
#pragma unroll
        for (int k = 0; k < 4; k++) g[k] = h2u[(s[k] << 4) + cl];
#pragma unroll
        for (int k = 0; k < 4; k++) {
            float v = __expf(lrelu(e[k] + edl));
            acc0 += v * b2f((unsigned short)(g[k] & 0xffffu));
            acc1 += v * b2f((unsigned short)(g[k] >> 16));
            wsum += v;
        }
    }
    for (; i < end; i++) {
        int s = csr[i];
        float v = __expf(lrelu(es[s] + edl));
        unsigned int g = h2u[(s << 4) + cl];
        acc0 += v * b2f((unsigned short)(g & 0xffffu));
        acc1 += v * b2f((unsigned short)(g >> 16));
        wsum += v;
    }
    float r = 1.f / wsum;
    float2 bb = ((const float2*)b2)[cl];
    float2 o;
    o.x = acc0 * r + bb.x;
    o.y = acc1 * r + bb.y;
    ((float2*)out)[(size_t)n * 16 + cl] = o;
}

// ---------------------------------------------------------------------------
extern "C" void kernel_launch(void* const* d_in, const int* in_sizes, int n_in,
                              void* d_out, int out_size, void* d_ws, size_t ws_size,
                              hipStream_t stream) {
    const float* x      = (const float*)d_in[0];
    const int*   ei     = (const int*)  d_in[1];
    const float* W1     = (const float*)d_in[2];
    const float* a_src1 = (const float*)d_in[3];
    const float* a_dst1 = (const float*)d_in[4];
    const float* b1     = (const float*)d_in[5];
    const float* W2     = (const float*)d_in[6];
    const float* a_src2 = (const float*)d_in[7];
    const float* a_dst2 = (const float*)d_in[8];
    const float* b2     = (const float*)d_in[9];
    float* outp = (float*)d_out;

    const int N = in_sizes[0] / 128;   // 50000
    const int E = in_sizes[1] / 2;     // 800000
    const int Etot = E + N;            // 850000

    const int* src = ei;
    const int* dst = ei + E;

    const int nb    = (N + 127) >> 7;                // 391 buckets
    const int chunk = (Etot + NBLK - 1) / NBLK;      // 1661
    const int M = nb * NBLK;                         // 200192 scan elements
    const int nbA = (M + 1023) / 1024;               // 196

    // workspace layout (bytes); total ~48.8 MB
    char* w = (char*)d_ws;
    unsigned short* h1b = (unsigned short*)(w + 0);          // 12,800,000
    unsigned short* h1e = (unsigned short*)(w + 12800000);   // 12,800,000
    unsigned short* h2b = (unsigned short*)(w + 25600000);   //  3,200,000
    float* es1  = (float*)(w + 28800000);                    //    800,000
    float* ed1  = (float*)(w + 29600000);                    //    800,000
    float* es2  = (float*)(w + 30400000);                    //    200,000
    float* ed2  = (float*)(w + 30600000);                    //    200,000
    int*   ptr  = (int*)  (w + 30800000);                    //    200,064
    int*   bsum = (int*)  (w + 31000064);                    //      1,024
    int*   cnt  = (int*)  (w + 31001088);                    //    800,768
    int*   csr_src = (int*)(w + 31801856);                   //  3,400,000
    int2*  bkt  = (int2*) (w + 35201856);                    //  6,800,000
    _Float16* w1h = (_Float16*)(w + 42001856);               //  6,800,000 -> 48,801,856

    // --- Layer-1 GEMM + fused dots1 + fused hist ---
    gemm1_mfma_kernel<<<(N + 63) / 64, 256, 0, stream>>>(x, W1, a_src1, a_dst1,
                                                         h1b, es1, ed1, N,
                                                         dst, E, Etot, nb, chunk, cnt);

    // --- CSR build: scan -> partition -> finalize (ptr/csr_src/w1h) ---
    scanA_kernel<<<nbA, 1024, 0, stream>>>(cnt, bsum, M);
    scanB_kernel<<<1, 256, 0, stream>>>(bsum, nbA);
    partition_kernel<<<NBLK, 256, 0, stream>>>(src, dst, E, Etot, nb, chunk,
                                               cnt, bsum, bkt);
    finalize_kernel<<<nb, 256, 0, stream>>>(bkt, cnt, bsum, nb, es1, ed1,
                                            ptr, csr_src, w1h, N, Etot);

    // --- Layer 1 aggregate ---
    agg1_kernel<<<(N + 7) / 8, 256, 0, stream>>>((const uint2*)h1b, w1h,
                                                 csr_src, ptr, b1,
                                                 (uint2*)h1e, N);

    // --- Layer 2: GEMM + fused dots, then aggregate with inline weights ---
    gemm2_mfma_kernel<<<(N + 63) / 64, 256, 0, stream>>>(h1e, W2, a_src2, a_dst2,
                                                         h2b, es2, ed2, N);
    agg2_kernel<<<(N + 15) / 16, 256, 0, stream>>>((const unsigned int*)h2b, es2, ed2,
                                                   csr_src, ptr, b2, outp, N);
}

// Round 9
// 198.649 us; speedup vs baseline: 2.6223x; 1.0121x over previous
//
#include <hip/hip_runtime.h>
#include <hip/hip_bf16.h>

#define LRELU_SLOPE 0.2f
#define NB_SHIFT 7          // 128 dst-nodes per bucket
#define NBLK 512            // hist/partition parallel chunks

typedef __attribute__((ext_vector_type(8))) short short8;
typedef __attribute__((ext_vector_type(4))) float float4v;

// bf16 <-> fp32 helpers (raw ushort storage)
__device__ inline float b2f(unsigned short u) {
    union { unsigned int i; float f; } v; v.i = ((unsigned int)u) << 16; return v.f;
}
__device__ inline unsigned short f2b(float f) {
    union { float f; unsigned int i; } v; v.f = f;
    unsigned int x = v.i;
    unsigned int r = x + 0x7fffu + ((x >> 16) & 1u);   // round-to-nearest-even
    return (unsigned short)(r >> 16);
}
__device__ inline float lrelu(float x) { return x > 0.f ? x : LRELU_SLOPE * x; }

// ---------------------------------------------------------------------------
// GEMM1 (MFMA bf16) + fused dots1 + fused CSR hist (blocks < NBLK).
// ---------------------------------------------------------------------------
__global__ __launch_bounds__(256) void gemm1_mfma_kernel(
        const float* __restrict__ x, const float* __restrict__ W1,
        const float* __restrict__ a_src, const float* __restrict__ a_dst,
        unsigned short* __restrict__ h1b, float* __restrict__ es,
        float* __restrict__ ed, int N,
        const int* __restrict__ dst, int E, int Etot, int nb, int chunk,
        int* __restrict__ cnt) {
    __shared__ unsigned short xs[64][136];
    __shared__ unsigned short wt[128][136];
    int tid = threadIdx.x;
    int n0 = blockIdx.x * 64;

    for (int i = tid; i < 128 * 128; i += 256) {
        int k = i >> 7, n = i & 127;
        wt[n][k] = f2b(W1[i]);
    }
    for (int i = tid; i < 64 * 128; i += 256) {
        int r = i >> 7, k = i & 127;
        int row = n0 + r; if (row >= N) row = N - 1;
        xs[r][k] = f2b(x[(size_t)row * 128 + k]);
    }
    __syncthreads();

    int wave = tid >> 6;
    int lane = tid & 63;
    int lrow = lane & 15;
    int quad = lane >> 4;

    short8 afr[4];
#pragma unroll
    for (int kc = 0; kc < 4; kc++)
        afr[kc] = *(const short8*)&xs[wave * 16 + lrow][kc * 32 + quad * 8];
    __syncthreads();   // all waves' A-fragment reads done before xs is reused

#pragma unroll
    for (int ct = 0; ct < 8; ct++) {
        float4v acc = {0.f, 0.f, 0.f, 0.f};
#pragma unroll
        for (int kc = 0; kc < 4; kc++) {
            short8 bfr = *(const short8*)&wt[ct * 16 + lrow][kc * 32 + quad * 8];
            acc = __builtin_amdgcn_mfma_f32_16x16x32_bf16(afr[kc], bfr, acc, 0, 0, 0);
        }
#pragma unroll
        for (int r = 0; r < 4; r++) {
            int lr = wave * 16 + quad * 4 + r;
            int grow = n0 + lr;
            unsigned short hb = f2b(acc[r]);
            xs[lr][ct * 16 + lrow] = hb;           // stage result tile for dots
            if (grow < N)
                h1b[grow * 128 + ct * 16 + lrow] = hb;
        }
    }
    __syncthreads();   // xs result tile ready; wt reads done (reused below)

    // fused dots1: thread = (row, head); 32-channel dot per head
    int row = tid >> 2, h = tid & 3;
    int rg = n0 + row;
    if (rg < N) {
        const float* ap = a_src + h * 32;
        const float* bp = a_dst + h * 32;
        float s = 0.f, d = 0.f;
#pragma unroll
        for (int c2 = 0; c2 < 16; c2++) {
            unsigned int u = *(const unsigned int*)&xs[row][h * 32 + 2 * c2];
            float v0 = b2f((unsigned short)(u & 0xffffu));
            float v1 = b2f((unsigned short)(u >> 16));
            float2 a = *(const float2*)&ap[2 * c2];
            float2 b = *(const float2*)&bp[2 * c2];
            s += v0 * a.x + v1 * a.y;
            d += v0 * b.x + v1 * b.y;
        }
        es[rg * 4 + h] = s;
        ed[rg * 4 + h] = d;
    }

    // fused CSR histogram (reuses wt LDS; all threads hit the barriers)
    int* histm = (int*)&wt[0][0];
    int blk = blockIdx.x;
    if (blk < NBLK)
        for (int i = tid; i < nb; i += 256) histm[i] = 0;
    __syncthreads();
    if (blk < NBLK) {
        int lo = blk * chunk;
        int hi = lo + chunk; if (hi > Etot) hi = Etot;
        for (int i = lo + tid; i < hi; i += 256) {
            int d = (i < E) ? dst[i] : (i - E);
            atomicAdd(&histm[d >> NB_SHIFT], 1);
        }
    }
    __syncthreads();
    if (blk < NBLK)
        for (int b = tid; b < nb; b += 256)
            cnt[b * NBLK + blk] = histm[b];
}

// in-place block-local exclusive scan (1024/block) + block totals
__global__ __launch_bounds__(1024) void scanA_kernel(int* cnt, int* bsum, int M) {
    __shared__ int tile[1024];
    int i = blockIdx.x * 1024 + threadIdx.x;
    int v = (i < M) ? cnt[i] : 0;
    tile[threadIdx.x] = v;
    __syncthreads();
    for (int off = 1; off < 1024; off <<= 1) {
        int t = (threadIdx.x >= (unsigned)off) ? tile[threadIdx.x - off] : 0;
        __syncthreads();
        tile[threadIdx.x] += t;
        __syncthreads();
    }
    int incl = tile[threadIdx.x];
    if (i < M) cnt[i] = incl - v;
    if (threadIdx.x == 1023) bsum[blockIdx.x] = incl;
}

__global__ __launch_bounds__(256) void scanB_kernel(int* __restrict__ bsum, int nb) {
    __shared__ int tile[256];
    int v = (threadIdx.x < (unsigned)nb) ? bsum[threadIdx.x] : 0;
    tile[threadIdx.x] = v;
    __syncthreads();
    for (int off = 1; off < 256; off <<= 1) {
        int t = (threadIdx.x >= (unsigned)off) ? tile[threadIdx.x - off] : 0;
        __syncthreads();
        tile[threadIdx.x] += t;
        __syncthreads();
    }
    if (threadIdx.x < (unsigned)nb) bsum[threadIdx.x] = tile[threadIdx.x] - v;
}

// ---------------------------------------------------------------------------
// CSR build, pass 2: partition edges into bucket array (no global atomics).
// ---------------------------------------------------------------------------
__global__ __launch_bounds__(256) void partition_kernel(
        const int* __restrict__ src, const int* __restrict__ dst,
        int E, int Etot, int nb, int chunk,
        const int* __restrict__ cnt, const int* __restrict__ boff,
        int2* __restrict__ bkt) {
    __shared__ int cur[512];
    int blk = blockIdx.x;
    for (int b = threadIdx.x; b < nb; b += 256) {
        int idx = b * NBLK + blk;
        cur[b] = cnt[idx] + boff[idx >> 10];
    }
    __syncthreads();
    int lo = blk * chunk;
    int hi = lo + chunk; if (hi > Etot) hi = Etot;
    for (int i = lo + threadIdx.x; i < hi; i += 256) {
        int s, d;
        if (i < E) { s = src[i]; d = dst[i]; }
        else       { s = d = i - E; }
        int pos = atomicAdd(&cur[d >> NB_SHIFT], 1);
        bkt[pos] = make_int2(s, d);
    }
}

// ---------------------------------------------------------------------------
// CSR build, pass 3 (one block per bucket): degree count -> LDS scan -> ptr;
// place src indices at final CSR positions; fold in fp16 layer-1 edge weights.
// ---------------------------------------------------------------------------
__global__ __launch_bounds__(256) void finalize_kernel(
        const int2* __restrict__ bkt, const int* __restrict__ cnt,
        const int* __restrict__ boff, int nb,
        const float* __restrict__ es, const float* __restrict__ ed,
        int* __restrict__ ptr, int* __restrict__ csr_src,
        _Float16* __restrict__ w1h, int N, int Etot) {
    __shared__ int deg[128];
    __shared__ int scn[128];
    __shared__ int cur[128];
    int b = blockIdx.x;
    int idx0 = b * NBLK;
    int base = cnt[idx0] + boff[idx0 >> 10];
    int nextbase;
    if (b + 1 < nb) {
        int idx1 = (b + 1) * NBLK;
        nextbase = cnt[idx1] + boff[idx1 >> 10];
    } else nextbase = Etot;
    int count = nextbase - base;
    int node0 = b << NB_SHIFT;
    int nodes = N - node0; if (nodes > 128) nodes = 128;

    if (threadIdx.x < 128) deg[threadIdx.x] = 0;
    __syncthreads();
    for (int i = threadIdx.x; i < count; i += 256)
        atomicAdd(&deg[bkt[base + i].y - node0], 1);
    __syncthreads();
    int v = (threadIdx.x < 128) ? deg[threadIdx.x] : 0;
    if (threadIdx.x < 128) scn[threadIdx.x] = v;
    __syncthreads();
    for (int off = 1; off < 128; off <<= 1) {
        int t = (threadIdx.x < 128 && threadIdx.x >= (unsigned)off) ? scn[threadIdx.x - off] : 0;
        __syncthreads();
        if (threadIdx.x < 128) scn[threadIdx.x] += t;
        __syncthreads();
    }
    if (threadIdx.x < 128) {
        int excl = scn[threadIdx.x] - v;
        cur[threadIdx.x] = excl;
        if (threadIdx.x < nodes) ptr[node0 + threadIdx.x] = base + excl;
    }
    if (b == nb - 1 && threadIdx.x == 0) ptr[N] = Etot;
    __syncthreads();
    for (int i = threadIdx.x; i < count; i += 256) {
        int2 sd = bkt[base + i];
        int pos = base + atomicAdd(&cur[sd.y - node0], 1);
        csr_src[pos] = sd.x;
        float4 a = *(const float4*)&es[sd.x * 4];
        float4 bb = *(const float4*)&ed[sd.y * 4];
        union { _Float16 h[4]; uint2 u; } ww;
        ww.h[0] = (_Float16)__expf(lrelu(a.x + bb.x));
        ww.h[1] = (_Float16)__expf(lrelu(a.y + bb.y));
        ww.h[2] = (_Float16)__expf(lrelu(a.z + bb.z));
        ww.h[3] = (_Float16)__expf(lrelu(a.w + bb.w));
        *(uint2*)&w1h[(size_t)pos * 4] = ww.u;
    }
}

// ---------------------------------------------------------------------------
// GEMM2 (MFMA bf16) + fused dots2: h2b = bf16(h1e @ W2); es2/ed2 per row.
// ---------------------------------------------------------------------------
__global__ __launch_bounds__(256) void gemm2_mfma_kernel(
        const unsigned short* __restrict__ h1e, const float* __restrict__ W2,
        const float* __restrict__ a_src, const float* __restrict__ a_dst,
        unsigned short* __restrict__ h2b, float* __restrict__ es,
        float* __restrict__ ed, int N) {
    __shared__ unsigned short xs[64][136];
    __shared__ unsigned short wt[32][136];
    int tid = threadIdx.x;
    int n0 = blockIdx.x * 64;

    for (int i = tid; i < 128 * 32; i += 256) {
        int k = i >> 5, n = i & 31;
        wt[n][k] = f2b(W2[i]);
    }
    {
        const unsigned int* srcp = (const unsigned int*)(h1e + (size_t)n0 * 128);
        int rows = (N - n0) < 64 ? (N - n0) : 64;
        int maxu = rows * 64;
        for (int i = tid; i < 4096; i += 256) {
            unsigned int v = (i < maxu) ? srcp[i] : 0u;
            int r = i >> 6, cp = (i & 63) << 1;
            *(unsigned int*)&xs[r][cp] = v;
        }
    }
    __syncthreads();

    int wave = tid >> 6;
    int lane = tid & 63;
    int lrow = lane & 15;
    int quad = lane >> 4;

    short8 afr[4];
#pragma unroll
    for (int kc = 0; kc < 4; kc++)
        afr[kc] = *(const short8*)&xs[wave * 16 + lrow][kc * 32 + quad * 8];
    __syncthreads();

#pragma unroll
    for (int ct = 0; ct < 2; ct++) {
        float4v acc = {0.f, 0.f, 0.f, 0.f};
#pragma unroll
        for (int kc = 0; kc < 4; kc++) {
            short8 bfr = *(const short8*)&wt[ct * 16 + lrow][kc * 32 + quad * 8];
            acc = __builtin_amdgcn_mfma_f32_16x16x32_bf16(afr[kc], bfr, acc, 0, 0, 0);
        }
#pragma unroll
        for (int r = 0; r < 4; r++) {
            int lr = wave * 16 + quad * 4 + r;
            int grow = n0 + lr;
            unsigned short hb = f2b(acc[r]);
            xs[lr][ct * 16 + lrow] = hb;
            if (grow < N)
                h2b[(size_t)grow * 32 + ct * 16 + lrow] = hb;
        }
    }
    __syncthreads();

    // fused dots2 (1 head, 32 channels): threads 0..63 = rows
    if (tid < 64) {
        int rg = n0 + tid;
        if (rg < N) {
            float s = 0.f, d = 0.f;
#pragma unroll
            for (int c2 = 0; c2 < 16; c2++) {
                unsigned int u = *(const unsigned int*)&xs[tid][2 * c2];
                float v0 = b2f((unsigned short)(u & 0xffffu));
                float v1 = b2f((unsigned short)(u >> 16));
                float2 a = *(const float2*)&a_src[2 * c2];
                float2 b = *(const float2*)&a_dst[2 * c2];
                s += v0 * a.x + v1 * a.y;
                d += v0 * b.x + v1 * b.y;
            }
            es[rg] = s;
            ed[rg] = d;
        }
    }
}

// ---------------------------------------------------------------------------
// Aggregation layer 1: 16 lanes/node x 8 channels (uint4 = 16 B/lane; one
// quarter-wave dwordx4 covers the whole 256-B row).  4 nodes/wave, 16/block.
// Halves per-edge VMEM instructions and address-VALU vs R8.
// ---------------------------------------------------------------------------
__global__ __launch_bounds__(256) void agg1_kernel(
        const uint4* __restrict__ h1v, const _Float16* __restrict__ w1h,
        const int* __restrict__ csr, const int* __restrict__ ptr,
        const float* __restrict__ b1, uint4* __restrict__ h1e_v, int N) {
    int tid = threadIdx.x;
    int n = blockIdx.x * 16 + (tid >> 4);
    if (n >= N) return;
    int cl = tid & 15;           // 16-B granule: channels 8cl..8cl+7
    int h = cl >> 2;             // head
    int start = ptr[n], end = ptr[n + 1];
    float a0 = 0.f, a1 = 0.f, a2 = 0.f, a3 = 0.f;
    float a4 = 0.f, a5 = 0.f, a6 = 0.f, a7 = 0.f, ws = 0.f;
    int i = start;
    for (; i + 4 <= end; i += 4) {
        int s[4]; float v[4]; uint4 g[4];
#pragma unroll
        for (int k = 0; k < 4; k++) s[k] = csr[i + k];
#pragma unroll
        for (int k = 0; k < 4; k++) v[k] = (float)w1h[(size_t)(i + k) * 4 + h];
#pragma unroll
        for (int k = 0; k < 4; k++) g[k] = h1v[(s[k] << 4) + cl];
#pragma unroll
        for (int k = 0; k < 4; k++) {
            a0 += v[k] * b2f((unsigned short)(g[k].x & 0xffffu));
            a1 += v[k] * b2f((unsigned short)(g[k].x >> 16));
            a2 += v[k] * b2f((unsigned short)(g[k].y & 0xffffu));
            a3 += v[k] * b2f((unsigned short)(g[k].y >> 16));
            a4 += v[k] * b2f((unsigned short)(g[k].z & 0xffffu));
            a5 += v[k] * b2f((unsigned short)(g[k].z >> 16));
            a6 += v[k] * b2f((unsigned short)(g[k].w & 0xffffu));
            a7 += v[k] * b2f((unsigned short)(g[k].w >> 16));
            ws += v[k];
        }
    }
    for (; i < end; i++) {
        int s = csr[i];
        float v = (float)w1h[(size_t)i * 4 + h];
        uint4 g = h1v[(s << 4) + cl];
        a0 += v * b2f((unsigned short)(g.x & 0xffffu));
        a1 += v * b2f((unsigned short)(g.x >> 16));
        a2 += v * b2f((unsigned short)(g.y & 0xffffu));
        a3 += v * b2f((unsigned short)(g.y >> 16));
        a4 += v * b2f((unsigned short)(g.z & 0xffffu));
        a5 += v * b2f((unsigned short)(g.z >> 16));
        a6 += v * b2f((unsigned short)(g.w & 0xffffu));
        a7 += v * b2f((unsigned short)(g.w >> 16));
        ws += v;
    }
    float r = 1.f / ws;
    float4 bb0 = ((const float4*)b1)[cl * 2];
    float4 bb1 = ((const float4*)b1)[cl * 2 + 1];
    float o0 = a0 * r + bb0.x;
    float o1 = a1 * r + bb0.y;
    float o2 = a2 * r + bb0.z;
    float o3 = a3 * r + bb0.w;
    float o4 = a4 * r + bb1.x;
    float o5 = a5 * r + bb1.y;
    float o6 = a6 * r + bb1.z;
    float o7 = a7 * r + bb1.w;
    o0 = o0 > 0.f ? o0 : __expf(o0) - 1.f;
    o1 = o1 > 0.f ? o1 : __expf(o1) - 1.f;
    o2 = o2 > 0.f ? o2 : __expf(o2) - 1.f;
    o3 = o3 > 0.f ? o3 : __expf(o3) - 1.f;
    o4 = o4 > 0.f ? o4 : __expf(o4) - 1.f;
    o5 = o5 > 0.f ? o5 : __expf(o5) - 1.f;
    o6 = o6 > 0.f ? o6 : __expf(o6) - 1.f;
    o7 = o7 > 0.f ? o7 : __expf(o7) - 1.f;
    uint4 outv;
    outv.x = (unsigned int)f2b(o0) | ((unsigned int)f2b(o1) << 16);
    outv.y = (unsigned int)f2b(o2) | ((unsigned int)f2b(o3) << 16);
    outv.z = (unsigned int)f2b(o4) | ((unsigned int)f2b(o5) << 16);
    outv.w = (unsigned int)f2b(o6) | ((unsigned int)f2b(o7) << 16);
    h1e_v[(n << 4) + cl] = outv;
}

// ---------------------------------------------------------------------------
// Aggregation layer 2: 8 lanes/node x 4 channels (uint2 = one 64-B line per
// edge), 8 nodes/wave, 32/block; unroll x8; inline exp weights.
// ---------------------------------------------------------------------------
__global__ __launch_bounds__(256) void agg2_kernel(
        const uint2* __restrict__ h2v, const float* __restrict__ es,
        const float* __restrict__ ed, const int* __restrict__ csr,
        const int* __restrict__ ptr, const float* __restrict__ b2,
        float* __restrict__ out, int N) {
    int tid = threadIdx.x;
    int n = blockIdx.x * 32 + (tid >> 3);
    if (n >= N) return;
    int cl = tid & 7;            // channels 4cl..4cl+3
    float edl = ed[n];
    int start = ptr[n], end = ptr[n + 1];
    float a0 = 0.f, a1 = 0.f, a2 = 0.f, a3 = 0.f, ws = 0.f;
    int i = start;
    for (; i + 8 <= end; i += 8) {
        int s[8]; float e[8]; uint2 g[8];
#pragma unroll
        for (int k = 0; k < 8; k++) s[k] = csr[i + k];
#pragma unroll
        for (int k = 0; k < 8; k++) e[k] = es[s[k]];
#pragma unroll
        for (int k = 0; k < 8; k++) g[k] = h2v[(s[k] << 3) + cl];
#pragma unroll
        for (int k = 0; k < 8; k++) {
            float v = __expf(lrelu(e[k] + edl));
            a0 += v * b2f((unsigned short)(g[k].x & 0xffffu));
            a1 += v * b2f((unsigned short)(g[k].x >> 16));
            a2 += v * b2f((unsigned short)(g[k].y & 0xffffu));
            a3 += v * b2f((unsigned short)(g[k].y >> 16));
            ws += v;
        }
    }
    for (; i < end; i++) {
        int s = csr[i];
        float v = __expf(lrelu(es[s] + edl));
        uint2 g = h2v[(s << 3) + cl];
        a0 += v * b2f((unsigned short)(g.x & 0xffffu));
        a1 += v * b2f((unsigned short)(g.x >> 16));
        a2 += v * b2f((unsigned short)(g.y & 0xffffu));
        a3 += v * b2f((unsigned short)(g.y >> 16));
        ws += v;
    }
    float r = 1.f / ws;
    float4 bb = ((const float4*)b2)[cl];
    float4 o;
    o.x = a0 * r + bb.x;
    o.y = a1 * r + bb.y;
    o.z = a2 * r + bb.z;
    o.w = a3 * r + bb.w;
    ((float4*)out)[(size_t)n * 8 + cl] = o;
}

// ---------------------------------------------------------------------------
extern "C" void kernel_launch(void* const* d_in, const int* in_sizes, int n_in,
                              void* d_out, int out_size, void* d_ws, size_t ws_size,
                              hipStream_t stream) {
    const float* x      = (const float*)d_in[0];
    const int*   ei     = (const int*)  d_in[1];
    const float* W1     = (const float*)d_in[2];
    const float* a_src1 = (const float*)d_in[3];
    const float* a_dst1 = (const float*)d_in[4];
    const float* b1     = (const float*)d_in[5];
    const float* W2     = (const float*)d_in[6];
    const float* a_src2 = (const float*)d_in[7];
    const float* a_dst2 = (const float*)d_in[8];
    const float* b2     = (const float*)d_in[9];
    float* outp = (float*)d_out;

    const int N = in_sizes[0] / 128;   // 50000
    const int E = in_sizes[1] / 2;     // 800000
    const int Etot = E + N;            // 850000

    const int* src = ei;
    const int* dst = ei + E;

    const int nb    = (N + 127) >> 7;                // 391 buckets
    const int chunk = (Etot + NBLK - 1) / NBLK;      // 1661
    const int M = nb * NBLK;                         // 200192 scan elements
    const int nbA = (M + 1023) / 1024;               // 196

    // workspace layout (bytes); total ~48.8 MB
    char* w = (char*)d_ws;
    unsigned short* h1b = (unsigned short*)(w + 0);          // 12,800,000
    unsigned short* h1e = (unsigned short*)(w + 12800000);   // 12,800,000
    unsigned short* h2b = (unsigned short*)(w + 25600000);   //  3,200,000
    float* es1  = (float*)(w + 28800000);                    //    800,000
    float* ed1  = (float*)(w + 29600000);                    //    800,000
    float* es2  = (float*)(w + 30400000);                    //    200,000
    float* ed2  = (float*)(w + 30600000);                    //    200,000
    int*   ptr  = (int*)  (w + 30800000);                    //    200,064
    int*   bsum = (int*)  (w + 31000064);                    //      1,024
    int*   cnt  = (int*)  (w + 31001088);                    //    800,768
    int*   csr_src = (int*)(w + 31801856);                   //  3,400,000
    int2*  bkt  = (int2*) (w + 35201856);                    //  6,800,000
    _Float16* w1h = (_Float16*)(w + 42001856);               //  6,800,000 -> 48,801,856

    // --- Layer-1 GEMM + fused dots1 + fused hist ---
    gemm1_mfma_kernel<<<(N + 63) / 64, 256, 0, stream>>>(x, W1, a_src1, a_dst1,
                                                         h1b, es1, ed1, N,
                                                         dst, E, Etot, nb, chunk, cnt);

    // --- CSR build: scan -> partition -> finalize (ptr/csr_src/w1h) ---
    scanA_kernel<<<nbA, 1024, 0, stream>>>(cnt, bsum, M);
    scanB_kernel<<<1, 256, 0, stream>>>(bsum, nbA);
    partition_kernel<<<NBLK, 256, 0, stream>>>(src, dst, E, Etot, nb, chunk,
                                               cnt, bsum, bkt);
    finalize_kernel<<<nb, 256, 0, stream>>>(bkt, cnt, bsum, nb, es1, ed1,
                                            ptr, csr_src, w1h, N, Etot);

    // --- Layer 1 aggregate ---
    agg1_kernel<<<(N + 15) / 16, 256, 0, stream>>>((const uint4*)h1b, w1h,
                                                   csr_src, ptr, b1,
                                                   (uint4*)h1e, N);

    // --- Layer 2: GEMM + fused dots, then aggregate with inline weights ---
    gemm2_mfma_kernel<<<(N + 63) / 64, 256, 0, stream>>>(h1e, W2, a_src2, a_dst2,
                                                         h2b, es2, ed2, N);
    agg2_kernel<<<(N + 31) / 32, 256, 0, stream>>>((const uint2*)h2b, es2, ed2,
                                                   csr_src, ptr, b2, outp, N);
}